// Round 4
// baseline (758.265 us; speedup 1.0000x reference)
//
#include <hip/hip_runtime.h>
#include <cstdint>

// LNGRU2dCell: B=16384, D=1024, S=1024
//   M1 = x @ Wi^T          (16384x4096, K=1024)
//   M2 = [s0|s1] @ Ws^T    (16384x4096, K=2048)
//   gates = LN(M1)*g1+b1 + LN(M2)*g2+b2 ; gate math ; out = LN(h)*gh+bh
//
// ws = 256 MB: M1 region [0,128MB) + M2 region [128,256MB).
// d_out (64 MB) doubles as cast scratch. Phases (lifetimes disjoint):
//   1. sb(64MB)->d_out, Wsb(16MB)->M1 region   [bf16 casts]
//   2. GEMM2 bf16 (sb,Wsb) -> M2
//   3. xb(32MB)+Wib(8MB)->d_out (sb dead)
//   4. GEMM1 bf16 (xb,Wib) -> M1 (Wsb dead)
//   5. fuse_ln(M1,M2,s0,s1) -> d_out (xb/Wib dead)
//
// R8 = R7 resubmit (R7 bench died at container level) + race fix:
// R7's ledger had A-early(t+2) staged at q2 into buf t&1 while half the
// waves still ds_read A-early rows of buf t&1 at q2 (qm=(q>>1)^gm makes
// each wave read one half of A-early at q0 and the other at q2). Moved
// the A-early stage to q3 (no ds_reads at q3; q2-end barrier guarantees
// all q2 reads drained). vmcnt ledger identical: at q3, outstanding =
// {Ae(t+1),Be(t+1),Al(t+1),Bl(t+1),Ae(t+2),Be(t+2)} = 12 loads/thread;
// vmcnt(4) drains tile t+1 fully, leaves the two t+2 units in flight.
//
// R7 core change (untested due to infra): no manual per-phase lgkmcnt(0)+
// sched_barrier(0) drain — that serialized the LDS pipe (2304 cy/K-tile,
// 192 ds_read_b128 @ ~12cy) against the matrix pipe (2483 cy/K-tile,
// 512 MFMA @ ~4.85cy) -> 42% MfmaUtil ceiling. Reads issued in consumption
// order (B-frags then A-frags), MFMAs ordered ii->jj->kh, so the compiler
// emits incremental per-use lgkmcnt(N) (m97-style) and the pipes overlap.
// Schedule per K-tile t (qm=(q>>1)^gm, qn=(q&1)^gb):
//   q0: read B0(4)+A0(8) | stage A-late(t+1) -> buf (t+1)&1 | bar | MFMA | bar
//   q1: read B1(4)       | stage B-late(t+1) -> buf (t+1)&1 | bar | MFMA | bar
//   q2: read A1(8)       | (no stage)                       | bar | MFMA | bar
//   q3: (no reads)       | stage A-early(t+2)+B-early(t+2) -> buf t&1
//                        | vmcnt(4) | bar | MFMA | bar
// A-early rows {0-63,192-255}, A-late {64-191}; B-early {0-31,96-127,
// 128-159,224-255}, B-late {32-95,160-223}. LDS swizzle: byte ^= (row&7)<<4
// on pre-swizzled global source + ds_read address (conflict-free, R6: 5e7->0).

typedef unsigned short ushort_t;
typedef __attribute__((ext_vector_type(8))) __bf16 bf16x8;
typedef __attribute__((ext_vector_type(4))) float f32x4;

__device__ __forceinline__ ushort_t f2b(float f) {  // RNE
    unsigned u = __float_as_uint(f);
    unsigned r = (u + 0x7fffu + ((u >> 16) & 1u)) >> 16;
    return (ushort_t)r;
}
__device__ __forceinline__ float b2f(ushort_t u) {
    return __uint_as_float(((unsigned)u) << 16);
}

__device__ __forceinline__ void gl_lds16(const void* g, void* l) {
    __builtin_amdgcn_global_load_lds(
        (const __attribute__((address_space(1))) unsigned int*)(uintptr_t)g,
        (__attribute__((address_space(3))) unsigned int*)(uintptr_t)l,
        16, 0, 0);
}

// fast transcendentals: v_exp_f32 is 2^x, v_rcp_f32 ~1ulp — both far below
// the bf16 noise floor of this pipeline.
#define LOG2E 1.4426950408889634f
__device__ __forceinline__ float fexp2(float x) { return __builtin_amdgcn_exp2f(x); }
__device__ __forceinline__ float frcp(float x)  { return __builtin_amdgcn_rcpf(x); }
__device__ __forceinline__ float fsigmoid(float x) {
    return frcp(1.f + fexp2(-LOG2E * x));   // x=+inf -> 1, x=-inf -> 0
}
__device__ __forceinline__ float ftanh(float y) {
    return 1.f - 2.f * frcp(1.f + fexp2((2.f * LOG2E) * y));  // saturates +-1
}

// ---------------- casts ----------------
__global__ __launch_bounds__(256) void cast_bf16(const float* __restrict__ src,
                                                 ushort_t* __restrict__ dst, long n) {
    long i = ((long)blockIdx.x * 256 + threadIdx.x) * 4;
    if (i + 3 < n) {
        float4 v = *(const float4*)(src + i);
        ushort4 u;
        u.x = f2b(v.x); u.y = f2b(v.y); u.z = f2b(v.z); u.w = f2b(v.w);
        *(ushort4*)(dst + i) = u;
    }
}

// dst is B x 2048, src0/src1 are B x 1024 each
__global__ __launch_bounds__(256) void cast_concat(const float* __restrict__ s0,
                                                   const float* __restrict__ s1,
                                                   ushort_t* __restrict__ dst) {
    long i = ((long)blockIdx.x * 256 + threadIdx.x) * 4;  // index in dst
    long row = i >> 11;
    int  col = (int)(i & 2047);
    const float* src = (col < 1024) ? (s0 + row * 1024 + col)
                                    : (s1 + row * 1024 + (col - 1024));
    float4 v = *(const float4*)src;
    ushort4 u;
    u.x = f2b(v.x); u.y = f2b(v.y); u.z = f2b(v.z); u.w = f2b(v.w);
    *(ushort4*)(dst + i) = u;
}

// ------- GEMM (bf16 in): C[MxN] = A[MxK] @ W[NxK]^T, fp32 accum, bf16 out ---

// stage one 16KB unit (2 x global_load_lds per thread). kt = target K-tile.
__device__ __forceinline__ void stage2(const char* s0, const char* s1,
                                       int d0, int d1, char* ldsbase,
                                       int kt, int NT) {
    if (kt < NT) {
        long kb = (long)kt << 7;                 // 64 bf16 = 128 bytes
        char* lb = ldsbase + ((kt & 1) << 15);   // 32 KB buffer stride
        gl_lds16(s0 + kb, lb + d0);
        gl_lds16(s1 + kb, lb + d1);
    }
}

__global__ __launch_bounds__(512, 2) void gemm_bt(const ushort_t* __restrict__ A,
                                                  const ushort_t* __restrict__ W,
                                                  ushort_t* __restrict__ C,
                                                  int M, int N, int K) {
    (void)M;
    __shared__ __align__(16) ushort_t As[2][256 * 64];   // 64 KB
    __shared__ __align__(16) ushort_t Bs[2][256 * 64];   // 64 KB

    const int NT   = K >> 6;          // K-tiles of 64
    const int t    = threadIdx.x;
    const int lane = t & 63;
    const int w    = t >> 6;
    const int gm   = w >> 2;          // 0/1: wave's M-half of the 256 rows
    const int gn   = w & 3;           // 0..3: wave's N-quarter
    const int gb   = gn & 1;          // qn stagger bit
    const int wm   = gm << 7;
    const int wn   = gn << 6;

    // T1: bijective XCD swizzle (nwg % 8 == 0 here: 64*16 = 1024)
    const int nwg  = gridDim.x;
    const int cpx  = nwg >> 3;
    const int orig = blockIdx.x;
    const int wgid = (orig & 7) * cpx + (orig >> 3);
    const int NXB  = N >> 8;
    const int bx   = wgid % NXB;
    const int by   = wgid / NXB;
    const int bm0  = by << 8;
    const int bn0  = bx << 8;

    // ---- staging precompute: thread t, loads n=0,1 -> unit row u = n*64+(t>>3)
    const int u0r = t >> 3;
    const int chb = (t & 7) << 4;                        // dest chunk byte (linear)
    const int cbs = chb ^ ((u0r & 7) << 4);              // swizzled SOURCE col byte
    const int ur0 = u0r, ur1 = 64 + u0r;                 // (ur&7 identical for both)

    // region maps (unit row -> actual tile row); all preserve row mod 8 == ur mod 8
    #define AER(ur) ((ur) < 64 ? (ur) : (ur) + 128)
    #define ALR(ur) ((ur) + 64)
    #define BER(ur) (((((ur) >> 5) >> 1) << 7) + ((((ur) >> 5) & 1) * 96) + ((ur) & 31))
    #define BLR(ur) ((ur) + 32 + (((ur) >> 6) << 6))

    const char* sAe0 = (const char*)(A + (long)(bm0 + AER(ur0)) * K) + cbs;
    const char* sAe1 = (const char*)(A + (long)(bm0 + AER(ur1)) * K) + cbs;
    const char* sAl0 = (const char*)(A + (long)(bm0 + ALR(ur0)) * K) + cbs;
    const char* sAl1 = (const char*)(A + (long)(bm0 + ALR(ur1)) * K) + cbs;
    const char* sBe0 = (const char*)(W + (long)(bn0 + BER(ur0)) * K) + cbs;
    const char* sBe1 = (const char*)(W + (long)(bn0 + BER(ur1)) * K) + cbs;
    const char* sBl0 = (const char*)(W + (long)(bn0 + BLR(ur0)) * K) + cbs;
    const char* sBl1 = (const char*)(W + (long)(bn0 + BLR(ur1)) * K) + cbs;

    const int dAe0 = AER(ur0) * 128 + chb, dAe1 = AER(ur1) * 128 + chb;
    const int dAl0 = ALR(ur0) * 128 + chb, dAl1 = ALR(ur1) * 128 + chb;
    const int dBe0 = BER(ur0) * 128 + chb, dBe1 = BER(ur1) * 128 + chb;
    const int dBl0 = BLR(ur0) * 128 + chb, dBl1 = BLR(ur1) * 128 + chb;

    char* Abase = (char*)&As[0][0];
    char* Bbase = (char*)&Bs[0][0];

    // ---- ds_read fragment precompute. Fragment row = 16*m + ml, so
    // row mod 8 = lane mod 8 -> read swizzle rsw = (lane&7)<<4.
    const int ml   = lane & 15;
    const int g    = lane >> 4;
    const int rsw  = (lane & 7) << 4;
    const int kc0  = ((g << 4)) ^ rsw;                   // kh=0 col byte
    const int kc1  = (64 | (g << 4)) ^ rsw;              // kh=1 col byte
    const int arow = (wm + ml) << 7;                     // byte row base
    const int brow = (wn + ml) << 7;

    f32x4 acc[4][4][2];                                  // [phase][ii][jj]
#pragma unroll
    for (int q = 0; q < 4; q++)
#pragma unroll
        for (int ii = 0; ii < 4; ii++)
#pragma unroll
            for (int jj = 0; jj < 2; jj++)
                acc[q][ii][jj] = (f32x4){0.f, 0.f, 0.f, 0.f};

    // ---- prologue: tile0 complete, then tile1 early units (stay in flight)
    stage2(sAe0, sAe1, dAe0, dAe1, Abase, 0, NT);
    stage2(sAl0, sAl1, dAl0, dAl1, Abase, 0, NT);
    stage2(sBe0, sBe1, dBe0, dBe1, Bbase, 0, NT);
    stage2(sBl0, sBl1, dBl0, dBl1, Bbase, 0, NT);
    stage2(sAe0, sAe1, dAe0, dAe1, Abase, 1, NT);
    stage2(sBe0, sBe1, dBe0, dBe1, Bbase, 1, NT);
    asm volatile("s_waitcnt vmcnt(4)" ::: "memory");     // tile 0 landed
    __builtin_amdgcn_s_barrier();

    for (int kt = 0; kt < NT; ++kt) {
        const char* Ab = Abase + ((kt & 1) << 15);
        const char* Bb = Bbase + ((kt & 1) << 15);
        bf16x8 af[4][2];          // A frags: read q0/q2, reused q1/q3
        bf16x8 bfr[2][2][2];      // B frags: [set=q&1][jj][kh], read q0/q1
#pragma unroll
        for (int q = 0; q < 4; ++q) {
            const int qm = (q >> 1) ^ gm;
            const int qn = (q & 1) ^ gb;

            // reads in consumption order: B-frags first, then A in ii order
            if (q < 2) {          // 4 ds_read_b128: B frags for this qn
#pragma unroll
                for (int jj = 0; jj < 2; jj++) {
                    const int ro = brow + ((qn << 1) + jj) * 2048;
                    bfr[q][jj][0] = *(const bf16x8*)(Bb + ro + kc0);
                    bfr[q][jj][1] = *(const bf16x8*)(Bb + ro + kc1);
                }
            }
            if ((q & 1) == 0) {   // 8 ds_read_b128: A frags for this qm
#pragma unroll
                for (int ii = 0; ii < 4; ii++) {
                    const int ro = arow + ((qm << 2) + ii) * 2048;
                    af[ii][0] = *(const bf16x8*)(Ab + ro + kc0);
                    af[ii][1] = *(const bf16x8*)(Ab + ro + kc1);
                }
            }

            // stage units (ledger in header; q3 stages both early units of
            // t+2 into buf t&1 — all reads of those regions drained at the
            // q2-end barrier, so no same-phase LDS write/read overlap).
            if (q == 0)      stage2(sAl0, sAl1, dAl0, dAl1, Abase, kt + 1, NT);
            else if (q == 1) stage2(sBl0, sBl1, dBl0, dBl1, Bbase, kt + 1, NT);
            else if (q == 3) {
                stage2(sAe0, sAe1, dAe0, dAe1, Abase, kt + 2, NT);
                stage2(sBe0, sBe1, dBe0, dBe1, Bbase, kt + 2, NT);
                if (kt < NT - 2) asm volatile("s_waitcnt vmcnt(4)" ::: "memory");
                else             asm volatile("s_waitcnt vmcnt(0)" ::: "memory");
            }
            __builtin_amdgcn_s_barrier();
            // NO manual lgkmcnt(0)/sched_barrier here: the compiler inserts
            // per-use lgkmcnt(N) waits, overlapping LDS reads with MFMA issue.
            __builtin_amdgcn_s_setprio(1);
#pragma unroll
            for (int ii = 0; ii < 4; ii++)
#pragma unroll
                for (int jj = 0; jj < 2; jj++)
#pragma unroll
                    for (int kh = 0; kh < 2; kh++)
                        acc[q][ii][jj] = __builtin_amdgcn_mfma_f32_16x16x32_bf16(
                            af[ii][kh], bfr[q & 1][jj][kh], acc[q][ii][jj], 0, 0, 0);
            __builtin_amdgcn_s_setprio(0);
            __builtin_amdgcn_s_barrier();
        }
    }

    // C/D layout: col=lane&15, row=(lane>>4)*4+r  [m89/m91 verified]
    const int quad = (lane >> 4) << 2;
#pragma unroll
    for (int q = 0; q < 4; ++q) {
        const int qm = (q >> 1) ^ gm;
        const int qn = (q & 1) ^ gb;
#pragma unroll
        for (int ii = 0; ii < 4; ii++)
#pragma unroll
            for (int jj = 0; jj < 2; jj++)
#pragma unroll
                for (int r = 0; r < 4; r++) {
                    const int cm = bm0 + wm + ((qm << 2) + ii) * 16 + quad + r;
                    const int cn = bn0 + wn + ((qn << 1) + jj) * 16 + ml;
                    C[(long)cm * N + cn] = f2b(acc[q][ii][jj][r]);
                }
    }
}

// ---------------- fused LN(M1)+LN(M2) -> gates -> h -> LN(h) ----------------
__global__ __launch_bounds__(256) void fuse_ln(const ushort_t* __restrict__ M1,
                                               const ushort_t* __restrict__ M2,
                                               const float* __restrict__ p0,
                                               const float* __restrict__ p1,
                                               const float* __restrict__ lni_g,
                                               const float* __restrict__ lni_b,
                                               const float* __restrict__ lns_g,
                                               const float* __restrict__ lns_b,
                                               const float* __restrict__ lnh_g,
                                               const float* __restrict__ lnh_b,
                                               float* __restrict__ out) {
    const int row = blockIdx.x;
    const int t   = threadIdx.x;
    const long base = (long)row * 4096;

    __shared__ float sred[16];
    __shared__ float stats[8];

    float v1[4][4], v2[4][4];
    float s1 = 0.f, q1 = 0.f, s2 = 0.f, q2 = 0.f;
#pragma unroll
    for (int q = 0; q < 4; q++) {
        ushort4 a = *(const ushort4*)(M1 + base + q * 1024 + t * 4);
        ushort4 b = *(const ushort4*)(M2 + base + q * 1024 + t * 4);
        const ushort_t* ap = (const ushort_t*)&a;
        const ushort_t* bp = (const ushort_t*)&b;
#pragma unroll
        for (int j = 0; j < 4; j++) {
            float f1 = b2f(ap[j]); v1[q][j] = f1; s1 += f1; q1 += f1 * f1;
            float f2 = b2f(bp[j]); v2[q][j] = f2; s2 += f2; q2 += f2 * f2;
        }
    }
    float r4[4] = {s1, q1, s2, q2};
#pragma unroll
    for (int off = 32; off > 0; off >>= 1) {
#pragma unroll
        for (int i = 0; i < 4; i++) r4[i] += __shfl_down(r4[i], off, 64);
    }
    if ((t & 63) == 0) {
        int w = t >> 6;
#pragma unroll
        for (int i = 0; i < 4; i++) sred[w * 4 + i] = r4[i];
    }
    __syncthreads();
    if (t == 0) {
        float S1 = 0, Q1 = 0, S2 = 0, Q2 = 0;
        for (int w = 0; w < 4; w++) {
            S1 += sred[w * 4]; Q1 += sred[w * 4 + 1];
            S2 += sred[w * 4 + 2]; Q2 += sred[w * 4 + 3];
        }
        float mu1 = S1 * (1.f / 4096.f), mu2 = S2 * (1.f / 4096.f);
        float var1 = Q1 * (1.f / 4096.f) - mu1 * mu1;
        float var2 = Q2 * (1.f / 4096.f) - mu2 * mu2;
        stats[0] = mu1; stats[1] = rsqrtf(var1 + 1e-5f);
        stats[2] = mu2; stats[3] = rsqrtf(var2 + 1e-5f);
    }
    __syncthreads();
    const float mu1 = stats[0], rs1 = stats[1], mu2 = stats[2], rs2 = stats[3];

    float4 Gi[4], Bi[4], Gs[4], Bs[4];
#pragma unroll
    for (int q = 0; q < 4; q++) {
        Gi[q] = *(const float4*)(lni_g + q * 1024 + t * 4);
        Bi[q] = *(const float4*)(lni_b + q * 1024 + t * 4);
        Gs[q] = *(const float4*)(lns_g + q * 1024 + t * 4);
        Bs[q] = *(const float4*)(lns_b + q * 1024 + t * 4);
    }
    float4 P0 = *(const float4*)(p0 + (long)row * 1024 + t * 4);
    float4 P1 = *(const float4*)(p1 + (long)row * 1024 + t * 4);

    float h[4];
    float sh = 0.f, qh = 0.f;
#pragma unroll
    for (int j = 0; j < 4; j++) {
        float gq[4], snv = 0.f;
#pragma unroll
        for (int q = 0; q < 4; q++) {
            float a = (v1[q][j] - mu1) * rs1 * ((const float*)&Gi[q])[j] + ((const float*)&Bi[q])[j];
            float b = (v2[q][j] - mu2) * rs2 * ((const float*)&Gs[q])[j] + ((const float*)&Bs[q])[j];
            if (q == 2) snv = b;
            gq[q] = a + b;
        }
        float rg = fsigmoid(gq[0]);
        float ig = fsigmoid(gq[1]);
        float lg = fsigmoid(gq[3]);
        float ng = ftanh(gq[2] - rg * snv);
        float pp0 = ((const float*)&P0)[j], pp1 = ((const float*)&P1)[j];
        float hv = ng + ig * (lg * pp0 + (1.f - lg) * pp1 - ng);
        h[j] = hv; sh += hv; qh += hv * hv;
    }
    float r2[2] = {sh, qh};
#pragma unroll
    for (int off = 32; off > 0; off >>= 1) {
#pragma unroll
        for (int i = 0; i < 2; i++) r2[i] += __shfl_down(r2[i], off, 64);
    }
    if ((t & 63) == 0) {
        int w = t >> 6;
        sred[w * 4] = r2[0]; sred[w * 4 + 1] = r2[1];
    }
    __syncthreads();
    if (t == 0) {
        float S = 0, Q = 0;
        for (int w = 0; w < 4; w++) { S += sred[w * 4]; Q += sred[w * 4 + 1]; }
        float mu = S * (1.f / 1024.f);
        float var = Q * (1.f / 1024.f) - mu * mu;
        stats[4] = mu; stats[5] = rsqrtf(var + 1e-5f);
    }
    __syncthreads();
    const float muh = stats[4], rsh = stats[5];

    float4 Gh = *(const float4*)(lnh_g + t * 4);
    float4 Bh = *(const float4*)(lnh_b + t * 4);
    float4 O;
#pragma unroll
    for (int j = 0; j < 4; j++)
        ((float*)&O)[j] = (h[j] - muh) * rsh * ((const float*)&Gh)[j] + ((const float*)&Bh)[j];
    *(float4*)(out + (long)row * 1024 + t * 4) = O;
}

extern "C" void kernel_launch(void* const* d_in, const int* in_sizes, int n_in,
                              void* d_out, int out_size, void* d_ws, size_t ws_size,
                              hipStream_t stream) {
    const float* x     = (const float*)d_in[0];
    const float* s0    = (const float*)d_in[1];
    const float* s1    = (const float*)d_in[2];
    const float* Wi    = (const float*)d_in[3];
    const float* Ws    = (const float*)d_in[4];
    const float* lni_g = (const float*)d_in[5];
    const float* lni_b = (const float*)d_in[6];
    const float* lns_g = (const float*)d_in[7];
    const float* lns_b = (const float*)d_in[8];
    const float* lnh_g = (const float*)d_in[9];
    const float* lnh_b = (const float*)d_in[10];
    float* out = (float*)d_out;

    // ws: 256 MB = M1 [0,128MB) + M2 [128,256MB). d_out = 64 MB cast scratch.
    char* wsb = (char*)d_ws;
    ushort_t* M1  = (ushort_t*)wsb;                           // 128 MB
    ushort_t* M2  = (ushort_t*)(wsb + (((size_t)128) << 20)); // 128 MB
    ushort_t* Wsb = (ushort_t*)wsb;                           // 16 MB, aliases M1 (dead)
    ushort_t* sb  = (ushort_t*)d_out;                         // 64 MB, aliases out
    ushort_t* xb  = (ushort_t*)d_out;                         // 32 MB, aliases out
    ushort_t* Wib = (ushort_t*)((char*)d_out + (((size_t)32) << 20));  // 8 MB

    // 256x256 tiles: grid = (16384/256)*(4096/256) = 64*16 = 1024 blocks
    dim3 g(1024);

    // phase 1: casts for GEMM2
    cast_concat<<<32768, 256, 0, stream>>>(s0, s1, sb);
    cast_bf16<<<8192, 256, 0, stream>>>(Ws, Wsb, (long)4096 * 2048);
    // phase 2: GEMM2 (K=2048) -> M2
    gemm_bt<<<g, 512, 0, stream>>>(sb, Wsb, M2, 16384, 4096, 2048);
    // phase 3: casts for GEMM1 (overwrite sb, now dead)
    cast_bf16<<<16384, 256, 0, stream>>>(x, xb, (long)16384 * 1024);
    cast_bf16<<<4096, 256, 0, stream>>>(Wi, Wib, (long)4096 * 1024);
    // phase 4: GEMM1 (K=1024) -> M1 (overwrites Wsb, now dead)
    gemm_bt<<<g, 512, 0, stream>>>(xb, Wib, M1, 16384, 4096, 1024);
    // phase 5: fused epilogue -> d_out (overwrites xb/Wib, now dead)
    fuse_ln<<<16384, 256, 0, stream>>>(M1, M2, s0, s1, lni_g, lni_b, lns_g,
                                       lns_b, lnh_g, lnh_b, out);
}

// Round 5
// 744.712 us; speedup vs baseline: 1.0182x; 1.0182x over previous
//
#include <hip/hip_runtime.h>
#include <cstdint>

// LNGRU2dCell: B=16384, D=1024, S=1024
//   M1 = x @ Wi^T          (16384x4096, K=1024)
//   M2 = [s0|s1] @ Ws^T    (16384x4096, K=2048)
//   gates = LN(M1)*g1+b1 + LN(M2)*g2+b2 ; gate math ; out = LN(h)*gh+bh
//
// ws = 256 MB: M1 region [0,128MB) + M2 region [128,256MB).
// d_out (64 MB) doubles as cast scratch. Phases (lifetimes disjoint):
//   1. sb(64MB)->d_out, Wsb(16MB)->M1 region   [bf16 casts]
//   2. GEMM2 bf16 (sb,Wsb) -> M2
//   3. xb(32MB)+Wib(8MB)->d_out (sb dead)
//   4. GEMM1 bf16 (xb,Wib) -> M1 (Wsb dead)
//   5. fuse_ln(M1,M2,s0,s1) -> d_out (xb/Wib dead)
//
// R9: full one-phase-ahead fragment reads (m201's "4 or 8 ds_read/phase").
// R6/R8 read frags at the top of the consuming phase -> every phase's MFMA
// stalls behind a 32-96-deep CU-wide ds_read burst (q0: ~1100cy vs 155cy
// MFMA). Now each read is issued AFTER the MFMA cluster that last uses the
// old contents of the same register array (zero extra VGPR; WAR orders it):
//   q0: stage Al(t+1) | bar | MFMA A0B0 | read bfr1<-Bl(t)   | bar
//   q1: stage Bl(t+1) | bar | MFMA A0B1 | read af  <-Al(t)   | bar
//   q2: vmcnt(4)      | bar | MFMA A1B0 | read bfr0<-Be(t+1) | bar
//   q3: stage Ae(t+2)+Be(t+2); vmcnt(4|0 tail)
//                     | bar | MFMA A1B1 | read af  <-Ae(t+1) | bar
// Read distribution 4/8/4/8, zero in-phase read->use: every read has a
// full phase (bar+stage+bar) to drain before its consumer's lgkm wait.
// Ledger (re-audited): q2's vmcnt(4) drains Ae,Be(t+1) [staged q3(t-1)]
// before the q2/q3 read-aheads; q3's vmcnt(4) drains Al,Bl(t+1) before
// tile t+1's q0/q1 reads. Same-buffer stage targets (q3: Ae,Be of buf t)
// are region-disjoint from all concurrently-readable regions (Bl,Al).
// kt=NT-1 reads garbage (stages guarded off) into never-used regs: safe.
// Accumulation order & C-write identical to R6/R8 -> absmax unchanged.
// LDS swizzle: byte ^= (row&7)<<4 on pre-swizzled global source + ds_read
// address (conflict-free, R6-verified: 5e7 -> 0).

typedef unsigned short ushort_t;
typedef __attribute__((ext_vector_type(8))) __bf16 bf16x8;
typedef __attribute__((ext_vector_type(4))) float f32x4;

__device__ __forceinline__ ushort_t f2b(float f) {  // RNE
    unsigned u = __float_as_uint(f);
    unsigned r = (u + 0x7fffu + ((u >> 16) & 1u)) >> 16;
    return (ushort_t)r;
}
__device__ __forceinline__ float b2f(ushort_t u) {
    return __uint_as_float(((unsigned)u) << 16);
}

__device__ __forceinline__ void gl_lds16(const void* g, void* l) {
    __builtin_amdgcn_global_load_lds(
        (const __attribute__((address_space(1))) unsigned int*)(uintptr_t)g,
        (__attribute__((address_space(3))) unsigned int*)(uintptr_t)l,
        16, 0, 0);
}

// fast transcendentals: v_exp_f32 is 2^x, v_rcp_f32 ~1ulp — both far below
// the bf16 noise floor of this pipeline.
#define LOG2E 1.4426950408889634f
__device__ __forceinline__ float fexp2(float x) { return __builtin_amdgcn_exp2f(x); }
__device__ __forceinline__ float frcp(float x)  { return __builtin_amdgcn_rcpf(x); }
__device__ __forceinline__ float fsigmoid(float x) {
    return frcp(1.f + fexp2(-LOG2E * x));   // x=+inf -> 1, x=-inf -> 0
}
__device__ __forceinline__ float ftanh(float y) {
    return 1.f - 2.f * frcp(1.f + fexp2((2.f * LOG2E) * y));  // saturates +-1
}

// ---------------- casts ----------------
__global__ __launch_bounds__(256) void cast_bf16(const float* __restrict__ src,
                                                 ushort_t* __restrict__ dst, long n) {
    long i = ((long)blockIdx.x * 256 + threadIdx.x) * 4;
    if (i + 3 < n) {
        float4 v = *(const float4*)(src + i);
        ushort4 u;
        u.x = f2b(v.x); u.y = f2b(v.y); u.z = f2b(v.z); u.w = f2b(v.w);
        *(ushort4*)(dst + i) = u;
    }
}

// dst is B x 2048, src0/src1 are B x 1024 each
__global__ __launch_bounds__(256) void cast_concat(const float* __restrict__ s0,
                                                   const float* __restrict__ s1,
                                                   ushort_t* __restrict__ dst) {
    long i = ((long)blockIdx.x * 256 + threadIdx.x) * 4;  // index in dst
    long row = i >> 11;
    int  col = (int)(i & 2047);
    const float* src = (col < 1024) ? (s0 + row * 1024 + col)
                                    : (s1 + row * 1024 + (col - 1024));
    float4 v = *(const float4*)src;
    ushort4 u;
    u.x = f2b(v.x); u.y = f2b(v.y); u.z = f2b(v.z); u.w = f2b(v.w);
    *(ushort4*)(dst + i) = u;
}

// ------- GEMM (bf16 in): C[MxN] = A[MxK] @ W[NxK]^T, fp32 accum, bf16 out ---

// stage one 16KB unit (2 x global_load_lds per thread). kt = target K-tile.
__device__ __forceinline__ void stage2(const char* s0, const char* s1,
                                       int d0, int d1, char* ldsbase,
                                       int kt, int NT) {
    if (kt < NT) {
        long kb = (long)kt << 7;                 // 64 bf16 = 128 bytes
        char* lb = ldsbase + ((kt & 1) << 15);   // 32 KB buffer stride
        gl_lds16(s0 + kb, lb + d0);
        gl_lds16(s1 + kb, lb + d1);
    }
}

#define MFMA_PHASE(Q, BS)                                                     \
    _Pragma("unroll") for (int ii = 0; ii < 4; ii++)                          \
        _Pragma("unroll") for (int jj = 0; jj < 2; jj++)                      \
            _Pragma("unroll") for (int kh = 0; kh < 2; kh++)                  \
                acc[Q][ii][jj] = __builtin_amdgcn_mfma_f32_16x16x32_bf16(     \
                    af[ii][kh], bfr[BS][jj][kh], acc[Q][ii][jj], 0, 0, 0);

#define READ_B(BS, QN, BASE)                                                  \
    _Pragma("unroll") for (int jj = 0; jj < 2; jj++) {                        \
        const int ro = brow + (((QN) << 1) + jj) * 2048;                      \
        bfr[BS][jj][0] = *(const bf16x8*)((BASE) + ro + kc0);                 \
        bfr[BS][jj][1] = *(const bf16x8*)((BASE) + ro + kc1);                 \
    }

#define READ_A(QM, BASE)                                                      \
    _Pragma("unroll") for (int ii = 0; ii < 4; ii++) {                        \
        const int ro = arow + (((QM) << 2) + ii) * 2048;                      \
        af[ii][0] = *(const bf16x8*)((BASE) + ro + kc0);                      \
        af[ii][1] = *(const bf16x8*)((BASE) + ro + kc1);                      \
    }

__global__ __launch_bounds__(512, 2) void gemm_bt(const ushort_t* __restrict__ A,
                                                  const ushort_t* __restrict__ W,
                                                  ushort_t* __restrict__ C,
                                                  int M, int N, int K) {
    (void)M;
    __shared__ __align__(16) ushort_t As[2][256 * 64];   // 64 KB
    __shared__ __align__(16) ushort_t Bs[2][256 * 64];   // 64 KB

    const int NT   = K >> 6;          // K-tiles of 64
    const int t    = threadIdx.x;
    const int lane = t & 63;
    const int w    = t >> 6;
    const int gm   = w >> 2;          // 0/1: wave's M-half of the 256 rows
    const int gn   = w & 3;           // 0..3: wave's N-quarter
    const int gb   = gn & 1;          // qn stagger bit
    const int wm   = gm << 7;
    const int wn   = gn << 6;

    // T1: bijective XCD swizzle (nwg % 8 == 0 here: 64*16 = 1024)
    const int nwg  = gridDim.x;
    const int cpx  = nwg >> 3;
    const int orig = blockIdx.x;
    const int wgid = (orig & 7) * cpx + (orig >> 3);
    const int NXB  = N >> 8;
    const int bx   = wgid % NXB;
    const int by   = wgid / NXB;
    const int bm0  = by << 8;
    const int bn0  = bx << 8;

    // ---- staging precompute: thread t, loads n=0,1 -> unit row u = n*64+(t>>3)
    const int u0r = t >> 3;
    const int chb = (t & 7) << 4;                        // dest chunk byte (linear)
    const int cbs = chb ^ ((u0r & 7) << 4);              // swizzled SOURCE col byte
    const int ur0 = u0r, ur1 = 64 + u0r;                 // (ur&7 identical for both)

    // region maps (unit row -> actual tile row); all preserve row mod 8 == ur mod 8
    #define AER(ur) ((ur) < 64 ? (ur) : (ur) + 128)
    #define ALR(ur) ((ur) + 64)
    #define BER(ur) (((((ur) >> 5) >> 1) << 7) + ((((ur) >> 5) & 1) * 96) + ((ur) & 31))
    #define BLR(ur) ((ur) + 32 + (((ur) >> 6) << 6))

    const char* sAe0 = (const char*)(A + (long)(bm0 + AER(ur0)) * K) + cbs;
    const char* sAe1 = (const char*)(A + (long)(bm0 + AER(ur1)) * K) + cbs;
    const char* sAl0 = (const char*)(A + (long)(bm0 + ALR(ur0)) * K) + cbs;
    const char* sAl1 = (const char*)(A + (long)(bm0 + ALR(ur1)) * K) + cbs;
    const char* sBe0 = (const char*)(W + (long)(bn0 + BER(ur0)) * K) + cbs;
    const char* sBe1 = (const char*)(W + (long)(bn0 + BER(ur1)) * K) + cbs;
    const char* sBl0 = (const char*)(W + (long)(bn0 + BLR(ur0)) * K) + cbs;
    const char* sBl1 = (const char*)(W + (long)(bn0 + BLR(ur1)) * K) + cbs;

    const int dAe0 = AER(ur0) * 128 + chb, dAe1 = AER(ur1) * 128 + chb;
    const int dAl0 = ALR(ur0) * 128 + chb, dAl1 = ALR(ur1) * 128 + chb;
    const int dBe0 = BER(ur0) * 128 + chb, dBe1 = BER(ur1) * 128 + chb;
    const int dBl0 = BLR(ur0) * 128 + chb, dBl1 = BLR(ur1) * 128 + chb;

    char* Abase = (char*)&As[0][0];
    char* Bbase = (char*)&Bs[0][0];

    // ---- ds_read fragment precompute. Fragment row = 16*m + ml, so
    // row mod 8 = lane mod 8 -> read swizzle rsw = (lane&7)<<4.
    const int ml   = lane & 15;
    const int g    = lane >> 4;
    const int rsw  = (lane & 7) << 4;
    const int kc0  = ((g << 4)) ^ rsw;                   // kh=0 col byte
    const int kc1  = (64 | (g << 4)) ^ rsw;              // kh=1 col byte
    const int arow = (wm + ml) << 7;                     // byte row base
    const int brow = (wn + ml) << 7;

    f32x4 acc[4][4][2];                                  // [phase][ii][jj]
#pragma unroll
    for (int q = 0; q < 4; q++)
#pragma unroll
        for (int ii = 0; ii < 4; ii++)
#pragma unroll
            for (int jj = 0; jj < 2; jj++)
                acc[q][ii][jj] = (f32x4){0.f, 0.f, 0.f, 0.f};

    bf16x8 af[4][2];          // A frags: set0 (Ae) live q0-q1, set1 (Al) q2-q3
    bf16x8 bfr[2][2][2];      // B frags: [set][jj][kh]; set0=Be, set1=Bl

    // ---- prologue: tile0 complete, then tile1 early units (stay in flight)
    stage2(sAe0, sAe1, dAe0, dAe1, Abase, 0, NT);
    stage2(sAl0, sAl1, dAl0, dAl1, Abase, 0, NT);
    stage2(sBe0, sBe1, dBe0, dBe1, Bbase, 0, NT);
    stage2(sBl0, sBl1, dBl0, dBl1, Bbase, 0, NT);
    stage2(sAe0, sAe1, dAe0, dAe1, Abase, 1, NT);
    stage2(sBe0, sBe1, dBe0, dBe1, Bbase, 1, NT);
    asm volatile("s_waitcnt vmcnt(4)" ::: "memory");     // tile 0 landed
    __builtin_amdgcn_s_barrier();
    // preload tile-0 q0 operands (consumed at q0's MFMA via lgkm wait)
    READ_B(0, gb, Bbase);
    READ_A(gm, Abase);

    for (int kt = 0; kt < NT; ++kt) {
        const char* AbT = Abase + ((kt & 1) << 15);         // tile t buffer
        const char* BbT = Bbase + ((kt & 1) << 15);
        const char* AbN = Abase + (((kt + 1) & 1) << 15);   // tile t+1 buffer
        const char* BbN = Bbase + (((kt + 1) & 1) << 15);

        // ---- q0: MFMA A0B0 | read-ahead Bl(t)
        stage2(sAl0, sAl1, dAl0, dAl1, Abase, kt + 1, NT);
        __builtin_amdgcn_s_barrier();
        __builtin_amdgcn_s_setprio(1);
        MFMA_PHASE(0, 0);
        __builtin_amdgcn_s_setprio(0);
        READ_B(1, 1 ^ gb, BbT);
        __builtin_amdgcn_s_barrier();

        // ---- q1: MFMA A0B1 | read-ahead Al(t)
        stage2(sBl0, sBl1, dBl0, dBl1, Bbase, kt + 1, NT);
        __builtin_amdgcn_s_barrier();
        __builtin_amdgcn_s_setprio(1);
        MFMA_PHASE(1, 1);
        __builtin_amdgcn_s_setprio(0);
        READ_A(1 ^ gm, AbT);
        __builtin_amdgcn_s_barrier();

        // ---- q2: MFMA A1B0 | read-ahead Be(t+1)
        asm volatile("s_waitcnt vmcnt(4)" ::: "memory");    // Ae,Be(t+1) landed
        __builtin_amdgcn_s_barrier();
        __builtin_amdgcn_s_setprio(1);
        MFMA_PHASE(2, 0);
        __builtin_amdgcn_s_setprio(0);
        READ_B(0, gb, BbN);
        __builtin_amdgcn_s_barrier();

        // ---- q3: MFMA A1B1 | read-ahead Ae(t+1)
        stage2(sAe0, sAe1, dAe0, dAe1, Abase, kt + 2, NT);
        stage2(sBe0, sBe1, dBe0, dBe1, Bbase, kt + 2, NT);
        if (kt < NT - 2) asm volatile("s_waitcnt vmcnt(4)" ::: "memory");
        else             asm volatile("s_waitcnt vmcnt(0)" ::: "memory");
        __builtin_amdgcn_s_barrier();
        __builtin_amdgcn_s_setprio(1);
        MFMA_PHASE(3, 1);
        __builtin_amdgcn_s_setprio(0);
        READ_A(gm, AbN);
        __builtin_amdgcn_s_barrier();
    }

    // C/D layout: col=lane&15, row=(lane>>4)*4+r  [m89/m91 verified]
    const int quad = (lane >> 4) << 2;
#pragma unroll
    for (int q = 0; q < 4; ++q) {
        const int qm = (q >> 1) ^ gm;
        const int qn = (q & 1) ^ gb;
#pragma unroll
        for (int ii = 0; ii < 4; ii++)
#pragma unroll
            for (int jj = 0; jj < 2; jj++)
#pragma unroll
                for (int r = 0; r < 4; r++) {
                    const int cm = bm0 + wm + ((qm << 2) + ii) * 16 + quad + r;
                    const int cn = bn0 + wn + ((qn << 1) + jj) * 16 + ml;
                    C[(long)cm * N + cn] = f2b(acc[q][ii][jj][r]);
                }
    }
}

// ---------------- fused LN(M1)+LN(M2) -> gates -> h -> LN(h) ----------------
__global__ __launch_bounds__(256) void fuse_ln(const ushort_t* __restrict__ M1,
                                               const ushort_t* __restrict__ M2,
                                               const float* __restrict__ p0,
                                               const float* __restrict__ p1,
                                               const float* __restrict__ lni_g,
                                               const float* __restrict__ lni_b,
                                               const float* __restrict__ lns_g,
                                               const float* __restrict__ lns_b,
                                               const float* __restrict__ lnh_g,
                                               const float* __restrict__ lnh_b,
                                               float* __restrict__ out) {
    const int row = blockIdx.x;
    const int t   = threadIdx.x;
    const long base = (long)row * 4096;

    __shared__ float sred[16];
    __shared__ float stats[8];

    float v1[4][4], v2[4][4];
    float s1 = 0.f, q1 = 0.f, s2 = 0.f, q2 = 0.f;
#pragma unroll
    for (int q = 0; q < 4; q++) {
        ushort4 a = *(const ushort4*)(M1 + base + q * 1024 + t * 4);
        ushort4 b = *(const ushort4*)(M2 + base + q * 1024 + t * 4);
        const ushort_t* ap = (const ushort_t*)&a;
        const ushort_t* bp = (const ushort_t*)&b;
#pragma unroll
        for (int j = 0; j < 4; j++) {
            float f1 = b2f(ap[j]); v1[q][j] = f1; s1 += f1; q1 += f1 * f1;
            float f2 = b2f(bp[j]); v2[q][j] = f2; s2 += f2; q2 += f2 * f2;
        }
    }
    float r4[4] = {s1, q1, s2, q2};
#pragma unroll
    for (int off = 32; off > 0; off >>= 1) {
#pragma unroll
        for (int i = 0; i < 4; i++) r4[i] += __shfl_down(r4[i], off, 64);
    }
    if ((t & 63) == 0) {
        int w = t >> 6;
#pragma unroll
        for (int i = 0; i < 4; i++) sred[w * 4 + i] = r4[i];
    }
    __syncthreads();
    if (t == 0) {
        float S1 = 0, Q1 = 0, S2 = 0, Q2 = 0;
        for (int w = 0; w < 4; w++) {
            S1 += sred[w * 4]; Q1 += sred[w * 4 + 1];
            S2 += sred[w * 4 + 2]; Q2 += sred[w * 4 + 3];
        }
        float mu1 = S1 * (1.f / 4096.f), mu2 = S2 * (1.f / 4096.f);
        float var1 = Q1 * (1.f / 4096.f) - mu1 * mu1;
        float var2 = Q2 * (1.f / 4096.f) - mu2 * mu2;
        stats[0] = mu1; stats[1] = rsqrtf(var1 + 1e-5f);
        stats[2] = mu2; stats[3] = rsqrtf(var2 + 1e-5f);
    }
    __syncthreads();
    const float mu1 = stats[0], rs1 = stats[1], mu2 = stats[2], rs2 = stats[3];

    float4 Gi[4], Bi[4], Gs[4], Bs[4];
#pragma unroll
    for (int q = 0; q < 4; q++) {
        Gi[q] = *(const float4*)(lni_g + q * 1024 + t * 4);
        Bi[q] = *(const float4*)(lni_b + q * 1024 + t * 4);
        Gs[q] = *(const float4*)(lns_g + q * 1024 + t * 4);
        Bs[q] = *(const float4*)(lns_b + q * 1024 + t * 4);
    }
    float4 P0 = *(const float4*)(p0 + (long)row * 1024 + t * 4);
    float4 P1 = *(const float4*)(p1 + (long)row * 1024 + t * 4);

    float h[4];
    float sh = 0.f, qh = 0.f;
#pragma unroll
    for (int j = 0; j < 4; j++) {
        float gq[4], snv = 0.f;
#pragma unroll
        for (int q = 0; q < 4; q++) {
            float a = (v1[q][j] - mu1) * rs1 * ((const float*)&Gi[q])[j] + ((const float*)&Bi[q])[j];
            float b = (v2[q][j] - mu2) * rs2 * ((const float*)&Gs[q])[j] + ((const float*)&Bs[q])[j];
            if (q == 2) snv = b;
            gq[q] = a + b;
        }
        float rg = fsigmoid(gq[0]);
        float ig = fsigmoid(gq[1]);
        float lg = fsigmoid(gq[3]);
        float ng = ftanh(gq[2] - rg * snv);
        float pp0 = ((const float*)&P0)[j], pp1 = ((const float*)&P1)[j];
        float hv = ng + ig * (lg * pp0 + (1.f - lg) * pp1 - ng);
        h[j] = hv; sh += hv; qh += hv * hv;
    }
    float r2[2] = {sh, qh};
#pragma unroll
    for (int off = 32; off > 0; off >>= 1) {
#pragma unroll
        for (int i = 0; i < 2; i++) r2[i] += __shfl_down(r2[i], off, 64);
    }
    if ((t & 63) == 0) {
        int w = t >> 6;
        sred[w * 4] = r2[0]; sred[w * 4 + 1] = r2[1];
    }
    __syncthreads();
    if (t == 0) {
        float S = 0, Q = 0;
        for (int w = 0; w < 4; w++) { S += sred[w * 4]; Q += sred[w * 4 + 1]; }
        float mu = S * (1.f / 1024.f);
        float var = Q * (1.f / 1024.f) - mu * mu;
        stats[4] = mu; stats[5] = rsqrtf(var + 1e-5f);
    }
    __syncthreads();
    const float muh = stats[4], rsh = stats[5];

    float4 Gh = *(const float4*)(lnh_g + t * 4);
    float4 Bh = *(const float4*)(lnh_b + t * 4);
    float4 O;
#pragma unroll
    for (int j = 0; j < 4; j++)
        ((float*)&O)[j] = (h[j] - muh) * rsh * ((const float*)&Gh)[j] + ((const float*)&Bh)[j];
    *(float4*)(out + (long)row * 1024 + t * 4) = O;
}

extern "C" void kernel_launch(void* const* d_in, const int* in_sizes, int n_in,
                              void* d_out, int out_size, void* d_ws, size_t ws_size,
                              hipStream_t stream) {
    const float* x     = (const float*)d_in[0];
    const float* s0    = (const float*)d_in[1];
    const float* s1    = (const float*)d_in[2];
    const float* Wi    = (const float*)d_in[3];
    const float* Ws    = (const float*)d_in[4];
    const float* lni_g = (const float*)d_in[5];
    const float* lni_b = (const float*)d_in[6];
    const float* lns_g = (const float*)d_in[7];
    const float* lns_b = (const float*)d_in[8];
    const float* lnh_g = (const float*)d_in[9];
    const float* lnh_b = (const float*)d_in[10];
    float* out = (float*)d_out;

    // ws: 256 MB = M1 [0,128MB) + M2 [128,256MB). d_out = 64 MB cast scratch.
    char* wsb = (char*)d_ws;
    ushort_t* M1  = (ushort_t*)wsb;                           // 128 MB
    ushort_t* M2  = (ushort_t*)(wsb + (((size_t)128) << 20)); // 128 MB
    ushort_t* Wsb = (ushort_t*)wsb;                           // 16 MB, aliases M1 (dead)
    ushort_t* sb  = (ushort_t*)d_out;                         // 64 MB, aliases out
    ushort_t* xb  = (ushort_t*)d_out;                         // 32 MB, aliases out
    ushort_t* Wib = (ushort_t*)((char*)d_out + (((size_t)32) << 20));  // 8 MB

    // 256x256 tiles: grid = (16384/256)*(4096/256) = 64*16 = 1024 blocks
    dim3 g(1024);

    // phase 1: casts for GEMM2
    cast_concat<<<32768, 256, 0, stream>>>(s0, s1, sb);
    cast_bf16<<<8192, 256, 0, stream>>>(Ws, Wsb, (long)4096 * 2048);
    // phase 2: GEMM2 (K=2048) -> M2
    gemm_bt<<<g, 512, 0, stream>>>(sb, Wsb, M2, 16384, 4096, 2048);
    // phase 3: casts for GEMM1 (overwrite sb, now dead)
    cast_bf16<<<16384, 256, 0, stream>>>(x, xb, (long)16384 * 1024);
    cast_bf16<<<4096, 256, 0, stream>>>(Wi, Wib, (long)4096 * 1024);
    // phase 4: GEMM1 (K=1024) -> M1 (overwrites Wsb, now dead)
    gemm_bt<<<g, 512, 0, stream>>>(xb, Wib, M1, 16384, 4096, 1024);
    // phase 5: fused epilogue -> d_out (overwrites xb/Wib, now dead)
    fuse_ln<<<16384, 256, 0, stream>>>(M1, M2, s0, s1, lni_g, lni_b, lns_g,
                                       lns_b, lnh_g, lnh_b, out);
}

// Round 6
// 744.208 us; speedup vs baseline: 1.0189x; 1.0007x over previous
//
#include <hip/hip_runtime.h>
#include <cstdint>

// LNGRU2dCell: B=16384, D=1024, S=1024
//   M1 = x @ Wi^T          (16384x4096, K=1024)
//   M2 = [s0|s1] @ Ws^T    (16384x4096, K=2048)
//   gates = LN(M1)*g1+b1 + LN(M2)*g2+b2 ; gate math ; out = LN(h)*gh+bh
//
// ws = 256 MB: M1 region [0,128MB) + M2 region [128,256MB).
// d_out (64 MB) doubles as cast scratch. Phases (lifetimes disjoint):
//   1. sb(64MB)->d_out, Wsb(16MB)->M1 region   [bf16 casts]
//   2. GEMM2 bf16 (sb,Wsb) -> M2
//   3. xb(32MB)+Wib(8MB)->d_out (sb dead)
//   4. GEMM1 bf16 (xb,Wib) -> M1 (Wsb dead)
//   5. fuse_ln(M1,M2,s0,s1) -> d_out (xb/Wib dead)
//
// R10: interleave next-phase ds_read_b128 INSIDE the MFMA issue burst,
// pinned with sched_group_barrier. Mechanism (R9 post-mortem): per phase
// per SIMD the 32 MFMAs occupy ~621cy of ISSUE-stall (matrix pipe accepts
// 1/~19cy; a stalled wave issues nothing after it). R9 placed reads after
// the cluster -> LDS drain (~576cy) ran with the matrix pipe idle ->
// 1260cy/phase (measured). Now reads sit in WAR-legal slots between MFMA
// groups, so the LDS pipe drains DURING the matrix issue-stall:
//   q0: {4 MFMA(ii,afE,bfr0), 1 rd bfr1<-Bl(t)}x4
//   q1: {4 MFMA(ii,afE,bfr1), 2 rd af[ii]<-Al(t)}x4      (af[ii] dead after its group)
//   q2: {8 MFMA(jj,afL,bfr0), 2 rd bfr0[jj]<-Be(t+1)}x2  (jj-major; bfr0[jj] dead after)
//   q3: {4 MFMA(ii,afL,bfr1), 2 rd af[ii]<-Ae(t+1)}x4
// Per-acc-element update order (kh0->kh1) unchanged in all phases ->
// bitwise-identical C -> absmax unchanged. vmcnt ledger identical to R9:
//   q2-top vmcnt(4) drains Ae,Be(t+1) [staged q3(t-1)] before q2/q3 reads;
//   q3 stages Ae,Be(t+2) then vmcnt(4) drains Al,Bl(t+1) [staged q0/q1]
//   before next-tile reads; tails vmcnt(0). All LDS stage targets are
//   region- or buffer-disjoint from any concurrently-readable region
//   (re-audited; unchanged from R9's passing schedule).
// LDS swizzle: byte ^= (row&7)<<4 on pre-swizzled global source + ds_read
// address (conflict-free, R6-verified: 5e7 -> 0).

typedef unsigned short ushort_t;
typedef __attribute__((ext_vector_type(8))) __bf16 bf16x8;
typedef __attribute__((ext_vector_type(4))) float f32x4;

__device__ __forceinline__ ushort_t f2b(float f) {  // RNE
    unsigned u = __float_as_uint(f);
    unsigned r = (u + 0x7fffu + ((u >> 16) & 1u)) >> 16;
    return (ushort_t)r;
}
__device__ __forceinline__ float b2f(ushort_t u) {
    return __uint_as_float(((unsigned)u) << 16);
}

__device__ __forceinline__ void gl_lds16(const void* g, void* l) {
    __builtin_amdgcn_global_load_lds(
        (const __attribute__((address_space(1))) unsigned int*)(uintptr_t)g,
        (__attribute__((address_space(3))) unsigned int*)(uintptr_t)l,
        16, 0, 0);
}

// fast transcendentals: v_exp_f32 is 2^x, v_rcp_f32 ~1ulp — both far below
// the bf16 noise floor of this pipeline.
#define LOG2E 1.4426950408889634f
__device__ __forceinline__ float fexp2(float x) { return __builtin_amdgcn_exp2f(x); }
__device__ __forceinline__ float frcp(float x)  { return __builtin_amdgcn_rcpf(x); }
__device__ __forceinline__ float fsigmoid(float x) {
    return frcp(1.f + fexp2(-LOG2E * x));   // x=+inf -> 1, x=-inf -> 0
}
__device__ __forceinline__ float ftanh(float y) {
    return 1.f - 2.f * frcp(1.f + fexp2((2.f * LOG2E) * y));  // saturates +-1
}

// ---------------- casts ----------------
__global__ __launch_bounds__(256) void cast_bf16(const float* __restrict__ src,
                                                 ushort_t* __restrict__ dst, long n) {
    long i = ((long)blockIdx.x * 256 + threadIdx.x) * 4;
    if (i + 3 < n) {
        float4 v = *(const float4*)(src + i);
        ushort4 u;
        u.x = f2b(v.x); u.y = f2b(v.y); u.z = f2b(v.z); u.w = f2b(v.w);
        *(ushort4*)(dst + i) = u;
    }
}

// dst is B x 2048, src0/src1 are B x 1024 each
__global__ __launch_bounds__(256) void cast_concat(const float* __restrict__ s0,
                                                   const float* __restrict__ s1,
                                                   ushort_t* __restrict__ dst) {
    long i = ((long)blockIdx.x * 256 + threadIdx.x) * 4;  // index in dst
    long row = i >> 11;
    int  col = (int)(i & 2047);
    const float* src = (col < 1024) ? (s0 + row * 1024 + col)
                                    : (s1 + row * 1024 + (col - 1024));
    float4 v = *(const float4*)src;
    ushort4 u;
    u.x = f2b(v.x); u.y = f2b(v.y); u.z = f2b(v.z); u.w = f2b(v.w);
    *(ushort4*)(dst + i) = u;
}

// ------- GEMM (bf16 in): C[MxN] = A[MxK] @ W[NxK]^T, fp32 accum, bf16 out ---

// stage one 16KB unit (2 x global_load_lds per thread). kt = target K-tile.
__device__ __forceinline__ void stage2(const char* s0, const char* s1,
                                       int d0, int d1, char* ldsbase,
                                       int kt, int NT) {
    if (kt < NT) {
        long kb = (long)kt << 7;                 // 64 bf16 = 128 bytes
        char* lb = ldsbase + ((kt & 1) << 15);   // 32 KB buffer stride
        gl_lds16(s0 + kb, lb + d0);
        gl_lds16(s1 + kb, lb + d1);
    }
}

#define SGB_MFMA(n) __builtin_amdgcn_sched_group_barrier(0x8, n, 0)
#define SGB_DSR(n)  __builtin_amdgcn_sched_group_barrier(0x100, n, 0)

// 4 MFMAs of one ii-group (jj,kh inner; per-element kh0->kh1)
#define MFMA_II(Q, II, BS)                                                    \
    _Pragma("unroll") for (int jj = 0; jj < 2; jj++)                          \
        _Pragma("unroll") for (int kh = 0; kh < 2; kh++)                      \
            acc[Q][II][jj] = __builtin_amdgcn_mfma_f32_16x16x32_bf16(         \
                af[II][kh], bfr[BS][jj][kh], acc[Q][II][jj], 0, 0, 0);

// 8 MFMAs of one jj-group (ii,kh inner; per-element kh0->kh1)
#define MFMA_JJ(Q, JJ, BS)                                                    \
    _Pragma("unroll") for (int ii = 0; ii < 4; ii++)                          \
        _Pragma("unroll") for (int kh = 0; kh < 2; kh++)                      \
            acc[Q][ii][JJ] = __builtin_amdgcn_mfma_f32_16x16x32_bf16(         \
                af[ii][kh], bfr[BS][JJ][kh], acc[Q][ii][JJ], 0, 0, 0);

#define RD_B(BASE, R16, KC) (*(const bf16x8*)((BASE) + brow + (R16) * 2048 + (KC)))
#define RD_A(BASE, R16, KC) (*(const bf16x8*)((BASE) + arow + (R16) * 2048 + (KC)))

__global__ __launch_bounds__(512, 2) void gemm_bt(const ushort_t* __restrict__ A,
                                                  const ushort_t* __restrict__ W,
                                                  ushort_t* __restrict__ C,
                                                  int M, int N, int K) {
    (void)M;
    __shared__ __align__(16) ushort_t As[2][256 * 64];   // 64 KB
    __shared__ __align__(16) ushort_t Bs[2][256 * 64];   // 64 KB

    const int NT   = K >> 6;          // K-tiles of 64
    const int t    = threadIdx.x;
    const int lane = t & 63;
    const int w    = t >> 6;
    const int gm   = w >> 2;          // 0/1: wave's M-half of the 256 rows
    const int gn   = w & 3;           // 0..3: wave's N-quarter
    const int gb   = gn & 1;          // qn stagger bit
    const int wm   = gm << 7;
    const int wn   = gn << 6;

    // T1: bijective XCD swizzle (nwg % 8 == 0 here: 64*16 = 1024)
    const int nwg  = gridDim.x;
    const int cpx  = nwg >> 3;
    const int orig = blockIdx.x;
    const int wgid = (orig & 7) * cpx + (orig >> 3);
    const int NXB  = N >> 8;
    const int bx   = wgid % NXB;
    const int by   = wgid / NXB;
    const int bm0  = by << 8;
    const int bn0  = bx << 8;

    // ---- staging precompute: thread t, loads n=0,1 -> unit row u = n*64+(t>>3)
    const int u0r = t >> 3;
    const int chb = (t & 7) << 4;                        // dest chunk byte (linear)
    const int cbs = chb ^ ((u0r & 7) << 4);              // swizzled SOURCE col byte
    const int ur0 = u0r, ur1 = 64 + u0r;                 // (ur&7 identical for both)

    // region maps (unit row -> actual tile row); all preserve row mod 8 == ur mod 8
    #define AER(ur) ((ur) < 64 ? (ur) : (ur) + 128)
    #define ALR(ur) ((ur) + 64)
    #define BER(ur) (((((ur) >> 5) >> 1) << 7) + ((((ur) >> 5) & 1) * 96) + ((ur) & 31))
    #define BLR(ur) ((ur) + 32 + (((ur) >> 6) << 6))

    const char* sAe0 = (const char*)(A + (long)(bm0 + AER(ur0)) * K) + cbs;
    const char* sAe1 = (const char*)(A + (long)(bm0 + AER(ur1)) * K) + cbs;
    const char* sAl0 = (const char*)(A + (long)(bm0 + ALR(ur0)) * K) + cbs;
    const char* sAl1 = (const char*)(A + (long)(bm0 + ALR(ur1)) * K) + cbs;
    const char* sBe0 = (const char*)(W + (long)(bn0 + BER(ur0)) * K) + cbs;
    const char* sBe1 = (const char*)(W + (long)(bn0 + BER(ur1)) * K) + cbs;
    const char* sBl0 = (const char*)(W + (long)(bn0 + BLR(ur0)) * K) + cbs;
    const char* sBl1 = (const char*)(W + (long)(bn0 + BLR(ur1)) * K) + cbs;

    const int dAe0 = AER(ur0) * 128 + chb, dAe1 = AER(ur1) * 128 + chb;
    const int dAl0 = ALR(ur0) * 128 + chb, dAl1 = ALR(ur1) * 128 + chb;
    const int dBe0 = BER(ur0) * 128 + chb, dBe1 = BER(ur1) * 128 + chb;
    const int dBl0 = BLR(ur0) * 128 + chb, dBl1 = BLR(ur1) * 128 + chb;

    char* Abase = (char*)&As[0][0];
    char* Bbase = (char*)&Bs[0][0];

    // ---- ds_read fragment precompute. Fragment row = 16*m + ml, so
    // row mod 8 = lane mod 8 -> read swizzle rsw = (lane&7)<<4.
    const int ml   = lane & 15;
    const int g    = lane >> 4;
    const int rsw  = (lane & 7) << 4;
    const int kc0  = ((g << 4)) ^ rsw;                   // kh=0 col byte
    const int kc1  = (64 | (g << 4)) ^ rsw;              // kh=1 col byte
    const int arow = (wm + ml) << 7;                     // byte row base
    const int brow = (wn + ml) << 7;

    f32x4 acc[4][4][2];                                  // [phase][ii][jj]
#pragma unroll
    for (int q = 0; q < 4; q++)
#pragma unroll
        for (int ii = 0; ii < 4; ii++)
#pragma unroll
            for (int jj = 0; jj < 2; jj++)
                acc[q][ii][jj] = (f32x4){0.f, 0.f, 0.f, 0.f};

    bf16x8 af[4][2];          // A frags: holds Ae for q0/q1, Al for q2/q3
    bf16x8 bfr[2][2][2];      // B frags: [set][jj][kh]; set0=Be, set1=Bl

    // ---- prologue: tile0 complete, then tile1 early units (stay in flight)
    stage2(sAe0, sAe1, dAe0, dAe1, Abase, 0, NT);
    stage2(sAl0, sAl1, dAl0, dAl1, Abase, 0, NT);
    stage2(sBe0, sBe1, dBe0, dBe1, Bbase, 0, NT);
    stage2(sBl0, sBl1, dBl0, dBl1, Bbase, 0, NT);
    stage2(sAe0, sAe1, dAe0, dAe1, Abase, 1, NT);
    stage2(sBe0, sBe1, dBe0, dBe1, Bbase, 1, NT);
    asm volatile("s_waitcnt vmcnt(4)" ::: "memory");     // tile 0 landed
    __builtin_amdgcn_s_barrier();
    // preload tile-0 q0 operands
#pragma unroll
    for (int jj = 0; jj < 2; jj++) {
        bfr[0][jj][0] = RD_B(Bbase, (gb << 1) + jj, kc0);
        bfr[0][jj][1] = RD_B(Bbase, (gb << 1) + jj, kc1);
    }
#pragma unroll
    for (int ii = 0; ii < 4; ii++) {
        af[ii][0] = RD_A(Abase, (gm << 2) + ii, kc0);
        af[ii][1] = RD_A(Abase, (gm << 2) + ii, kc1);
    }

    for (int kt = 0; kt < NT; ++kt) {
        const char* AbT = Abase + ((kt & 1) << 15);         // tile t buffer
        const char* BbT = Bbase + ((kt & 1) << 15);
        const char* AbN = Abase + (((kt + 1) & 1) << 15);   // tile t+1 buffer
        const char* BbN = Bbase + (((kt + 1) & 1) << 15);
        const int rB1 = (1 ^ gb) << 1;   // Bl rows for bfr1
        const int rB0 = gb << 1;         // Be rows for bfr0
        const int rA1 = (1 ^ gm) << 2;   // Al rows
        const int rA0 = gm << 2;         // Ae rows

        // ---- q0: MFMA(afE,bfr0) ∥ read bfr1<-Bl(t)
        stage2(sAl0, sAl1, dAl0, dAl1, Abase, kt + 1, NT);
        __builtin_amdgcn_s_barrier();
        __builtin_amdgcn_s_setprio(1);
        MFMA_II(0, 0, 0); SGB_MFMA(4);
        bfr[1][0][0] = RD_B(BbT, rB1 + 0, kc0); SGB_DSR(1);
        MFMA_II(0, 1, 0); SGB_MFMA(4);
        bfr[1][0][1] = RD_B(BbT, rB1 + 0, kc1); SGB_DSR(1);
        MFMA_II(0, 2, 0); SGB_MFMA(4);
        bfr[1][1][0] = RD_B(BbT, rB1 + 1, kc0); SGB_DSR(1);
        MFMA_II(0, 3, 0); SGB_MFMA(4);
        bfr[1][1][1] = RD_B(BbT, rB1 + 1, kc1); SGB_DSR(1);
        __builtin_amdgcn_s_setprio(0);
        __builtin_amdgcn_s_barrier();

        // ---- q1: MFMA(afE,bfr1) ∥ read af<-Al(t)  (af[ii] dead after its group)
        stage2(sBl0, sBl1, dBl0, dBl1, Bbase, kt + 1, NT);
        __builtin_amdgcn_s_barrier();
        __builtin_amdgcn_s_setprio(1);
        MFMA_II(1, 0, 1); SGB_MFMA(4);
        af[0][0] = RD_A(AbT, rA1 + 0, kc0);
        af[0][1] = RD_A(AbT, rA1 + 0, kc1); SGB_DSR(2);
        MFMA_II(1, 1, 1); SGB_MFMA(4);
        af[1][0] = RD_A(AbT, rA1 + 1, kc0);
        af[1][1] = RD_A(AbT, rA1 + 1, kc1); SGB_DSR(2);
        MFMA_II(1, 2, 1); SGB_MFMA(4);
        af[2][0] = RD_A(AbT, rA1 + 2, kc0);
        af[2][1] = RD_A(AbT, rA1 + 2, kc1); SGB_DSR(2);
        MFMA_II(1, 3, 1); SGB_MFMA(4);
        af[3][0] = RD_A(AbT, rA1 + 3, kc0);
        af[3][1] = RD_A(AbT, rA1 + 3, kc1); SGB_DSR(2);
        __builtin_amdgcn_s_setprio(0);
        __builtin_amdgcn_s_barrier();

        // ---- q2: MFMA(afL,bfr0) jj-major ∥ read bfr0<-Be(t+1)
        asm volatile("s_waitcnt vmcnt(4)" ::: "memory");    // Ae,Be(t+1) landed
        __builtin_amdgcn_s_barrier();
        __builtin_amdgcn_s_setprio(1);
        MFMA_JJ(2, 0, 0); SGB_MFMA(8);
        bfr[0][0][0] = RD_B(BbN, rB0 + 0, kc0);
        bfr[0][0][1] = RD_B(BbN, rB0 + 0, kc1); SGB_DSR(2);
        MFMA_JJ(2, 1, 0); SGB_MFMA(8);
        bfr[0][1][0] = RD_B(BbN, rB0 + 1, kc0);
        bfr[0][1][1] = RD_B(BbN, rB0 + 1, kc1); SGB_DSR(2);
        __builtin_amdgcn_s_setprio(0);
        __builtin_amdgcn_s_barrier();

        // ---- q3: MFMA(afL,bfr1) ∥ read af<-Ae(t+1)
        stage2(sAe0, sAe1, dAe0, dAe1, Abase, kt + 2, NT);
        stage2(sBe0, sBe1, dBe0, dBe1, Bbase, kt + 2, NT);
        if (kt < NT - 2) asm volatile("s_waitcnt vmcnt(4)" ::: "memory");
        else             asm volatile("s_waitcnt vmcnt(0)" ::: "memory");
        __builtin_amdgcn_s_barrier();
        __builtin_amdgcn_s_setprio(1);
        MFMA_II(3, 0, 1); SGB_MFMA(4);
        af[0][0] = RD_A(AbN, rA0 + 0, kc0);
        af[0][1] = RD_A(AbN, rA0 + 0, kc1); SGB_DSR(2);
        MFMA_II(3, 1, 1); SGB_MFMA(4);
        af[1][0] = RD_A(AbN, rA0 + 1, kc0);
        af[1][1] = RD_A(AbN, rA0 + 1, kc1); SGB_DSR(2);
        MFMA_II(3, 2, 1); SGB_MFMA(4);
        af[2][0] = RD_A(AbN, rA0 + 2, kc0);
        af[2][1] = RD_A(AbN, rA0 + 2, kc1); SGB_DSR(2);
        MFMA_II(3, 3, 1); SGB_MFMA(4);
        af[3][0] = RD_A(AbN, rA0 + 3, kc0);
        af[3][1] = RD_A(AbN, rA0 + 3, kc1); SGB_DSR(2);
        __builtin_amdgcn_s_setprio(0);
        __builtin_amdgcn_s_barrier();
    }

    // C/D layout: col=lane&15, row=(lane>>4)*4+r  [m89/m91 verified]
    const int quad = (lane >> 4) << 2;
#pragma unroll
    for (int q = 0; q < 4; ++q) {
        const int qm = (q >> 1) ^ gm;
        const int qn = (q & 1) ^ gb;
#pragma unroll
        for (int ii = 0; ii < 4; ii++)
#pragma unroll
            for (int jj = 0; jj < 2; jj++)
#pragma unroll
                for (int r = 0; r < 4; r++) {
                    const int cm = bm0 + wm + ((qm << 2) + ii) * 16 + quad + r;
                    const int cn = bn0 + wn + ((qn << 1) + jj) * 16 + ml;
                    C[(long)cm * N + cn] = f2b(acc[q][ii][jj][r]);
                }
    }
}

// ---------------- fused LN(M1)+LN(M2) -> gates -> h -> LN(h) ----------------
__global__ __launch_bounds__(256) void fuse_ln(const ushort_t* __restrict__ M1,
                                               const ushort_t* __restrict__ M2,
                                               const float* __restrict__ p0,
                                               const float* __restrict__ p1,
                                               const float* __restrict__ lni_g,
                                               const float* __restrict__ lni_b,
                                               const float* __restrict__ lns_g,
                                               const float* __restrict__ lns_b,
                                               const float* __restrict__ lnh_g,
                                               const float* __restrict__ lnh_b,
                                               float* __restrict__ out) {
    const int row = blockIdx.x;
    const int t   = threadIdx.x;
    const long base = (long)row * 4096;

    __shared__ float sred[16];
    __shared__ float stats[8];

    float v1[4][4], v2[4][4];
    float s1 = 0.f, q1 = 0.f, s2 = 0.f, q2 = 0.f;
#pragma unroll
    for (int q = 0; q < 4; q++) {
        ushort4 a = *(const ushort4*)(M1 + base + q * 1024 + t * 4);
        ushort4 b = *(const ushort4*)(M2 + base + q * 1024 + t * 4);
        const ushort_t* ap = (const ushort_t*)&a;
        const ushort_t* bp = (const ushort_t*)&b;
#pragma unroll
        for (int j = 0; j < 4; j++) {
            float f1 = b2f(ap[j]); v1[q][j] = f1; s1 += f1; q1 += f1 * f1;
            float f2 = b2f(bp[j]); v2[q][j] = f2; s2 += f2; q2 += f2 * f2;
        }
    }
    float r4[4] = {s1, q1, s2, q2};
#pragma unroll
    for (int off = 32; off > 0; off >>= 1) {
#pragma unroll
        for (int i = 0; i < 4; i++) r4[i] += __shfl_down(r4[i], off, 64);
    }
    if ((t & 63) == 0) {
        int w = t >> 6;
#pragma unroll
        for (int i = 0; i < 4; i++) sred[w * 4 + i] = r4[i];
    }
    __syncthreads();
    if (t == 0) {
        float S1 = 0, Q1 = 0, S2 = 0, Q2 = 0;
        for (int w = 0; w < 4; w++) {
            S1 += sred[w * 4]; Q1 += sred[w * 4 + 1];
            S2 += sred[w * 4 + 2]; Q2 += sred[w * 4 + 3];
        }
        float mu1 = S1 * (1.f / 4096.f), mu2 = S2 * (1.f / 4096.f);
        float var1 = Q1 * (1.f / 4096.f) - mu1 * mu1;
        float var2 = Q2 * (1.f / 4096.f) - mu2 * mu2;
        stats[0] = mu1; stats[1] = rsqrtf(var1 + 1e-5f);
        stats[2] = mu2; stats[3] = rsqrtf(var2 + 1e-5f);
    }
    __syncthreads();
    const float mu1 = stats[0], rs1 = stats[1], mu2 = stats[2], rs2 = stats[3];

    float4 Gi[4], Bi[4], Gs[4], Bs[4];
#pragma unroll
    for (int q = 0; q < 4; q++) {
        Gi[q] = *(const float4*)(lni_g + q * 1024 + t * 4);
        Bi[q] = *(const float4*)(lni_b + q * 1024 + t * 4);
        Gs[q] = *(const float4*)(lns_g + q * 1024 + t * 4);
        Bs[q] = *(const float4*)(lns_b + q * 1024 + t * 4);
    }
    float4 P0 = *(const float4*)(p0 + (long)row * 1024 + t * 4);
    float4 P1 = *(const float4*)(p1 + (long)row * 1024 + t * 4);

    float h[4];
    float sh = 0.f, qh = 0.f;
#pragma unroll
    for (int j = 0; j < 4; j++) {
        float gq[4], snv = 0.f;
#pragma unroll
        for (int q = 0; q < 4; q++) {
            float a = (v1[q][j] - mu1) * rs1 * ((const float*)&Gi[q])[j] + ((const float*)&Bi[q])[j];
            float b = (v2[q][j] - mu2) * rs2 * ((const float*)&Gs[q])[j] + ((const float*)&Bs[q])[j];
            if (q == 2) snv = b;
            gq[q] = a + b;
        }
        float rg = fsigmoid(gq[0]);
        float ig = fsigmoid(gq[1]);
        float lg = fsigmoid(gq[3]);
        float ng = ftanh(gq[2] - rg * snv);
        float pp0 = ((const float*)&P0)[j], pp1 = ((const float*)&P1)[j];
        float hv = ng + ig * (lg * pp0 + (1.f - lg) * pp1 - ng);
        h[j] = hv; sh += hv; qh += hv * hv;
    }
    float r2[2] = {sh, qh};
#pragma unroll
    for (int off = 32; off > 0; off >>= 1) {
#pragma unroll
        for (int i = 0; i < 2; i++) r2[i] += __shfl_down(r2[i], off, 64);
    }
    if ((t & 63) == 0) {
        int w = t >> 6;
        sred[w * 4] = r2[0]; sred[w * 4 + 1] = r2[1];
    }
    __syncthreads();
    if (t == 0) {
        float S = 0, Q = 0;
        for (int w = 0; w < 4; w++) { S += sred[w * 4]; Q += sred[w * 4 + 1]; }
        float mu = S * (1.f / 1024.f);
        float var = Q * (1.f / 1024.f) - mu * mu;
        stats[4] = mu; stats[5] = rsqrtf(var + 1e-5f);
    }
    __syncthreads();
    const float muh = stats[4], rsh = stats[5];

    float4 Gh = *(const float4*)(lnh_g + t * 4);
    float4 Bh = *(const float4*)(lnh_b + t * 4);
    float4 O;
#pragma unroll
    for (int j = 0; j < 4; j++)
        ((float*)&O)[j] = (h[j] - muh) * rsh * ((const float*)&Gh)[j] + ((const float*)&Bh)[j];
    *(float4*)(out + (long)row * 1024 + t * 4) = O;
}

extern "C" void kernel_launch(void* const* d_in, const int* in_sizes, int n_in,
                              void* d_out, int out_size, void* d_ws, size_t ws_size,
                              hipStream_t stream) {
    const float* x     = (const float*)d_in[0];
    const float* s0    = (const float*)d_in[1];
    const float* s1    = (const float*)d_in[2];
    const float* Wi    = (const float*)d_in[3];
    const float* Ws    = (const float*)d_in[4];
    const float* lni_g = (const float*)d_in[5];
    const float* lni_b = (const float*)d_in[6];
    const float* lns_g = (const float*)d_in[7];
    const float* lns_b = (const float*)d_in[8];
    const float* lnh_g = (const float*)d_in[9];
    const float* lnh_b = (const float*)d_in[10];
    float* out = (float*)d_out;

    // ws: 256 MB = M1 [0,128MB) + M2 [128,256MB). d_out = 64 MB cast scratch.
    char* wsb = (char*)d_ws;
    ushort_t* M1  = (ushort_t*)wsb;                           // 128 MB
    ushort_t* M2  = (ushort_t*)(wsb + (((size_t)128) << 20)); // 128 MB
    ushort_t* Wsb = (ushort_t*)wsb;                           // 16 MB, aliases M1 (dead)
    ushort_t* sb  = (ushort_t*)d_out;                         // 64 MB, aliases out
    ushort_t* xb  = (ushort_t*)d_out;                         // 32 MB, aliases out
    ushort_t* Wib = (ushort_t*)((char*)d_out + (((size_t)32) << 20));  // 8 MB

    // 256x256 tiles: grid = (16384/256)*(4096/256) = 64*16 = 1024 blocks
    dim3 g(1024);

    // phase 1: casts for GEMM2
    cast_concat<<<32768, 256, 0, stream>>>(s0, s1, sb);
    cast_bf16<<<8192, 256, 0, stream>>>(Ws, Wsb, (long)4096 * 2048);
    // phase 2: GEMM2 (K=2048) -> M2
    gemm_bt<<<g, 512, 0, stream>>>(sb, Wsb, M2, 16384, 4096, 2048);
    // phase 3: casts for GEMM1 (overwrite sb, now dead)
    cast_bf16<<<16384, 256, 0, stream>>>(x, xb, (long)16384 * 1024);
    cast_bf16<<<4096, 256, 0, stream>>>(Wi, Wib, (long)4096 * 1024);
    // phase 4: GEMM1 (K=1024) -> M1 (overwrites Wsb, now dead)
    gemm_bt<<<g, 512, 0, stream>>>(xb, Wib, M1, 16384, 4096, 1024);
    // phase 5: fused epilogue -> d_out (overwrites xb/Wib, now dead)
    fuse_ln<<<16384, 256, 0, stream>>>(M1, M2, s0, s1, lni_g, lni_b, lns_g,
                                       lns_b, lnh_g, lnh_b, out);
}

// Round 7
// 743.170 us; speedup vs baseline: 1.0203x; 1.0014x over previous
//
#include <hip/hip_runtime.h>
#include <cstdint>

// LNGRU2dCell: B=16384, D=1024, S=1024
//   M1 = x @ Wi^T          (16384x4096, K=1024)
//   M2 = [s0|s1] @ Ws^T    (16384x4096, K=2048)
//   gates = LN(M1)*g1+b1 + LN(M2)*g2+b2 ; gate math ; out = LN(h)*gh+bh
//
// ws = 256 MB: M1 region [0,128MB) + M2 region [128,256MB).
// d_out (64 MB) doubles as cast scratch. Phases (lifetimes disjoint):
//   1. sb(64MB)->d_out, Wsb(16MB)->M1 region   [bf16 casts]
//   2. GEMM2 bf16 (sb,Wsb) -> M2
//   3. xb(32MB)+Wib(8MB)->d_out (sb dead)
//   4. GEMM1 bf16 (xb,Wib) -> M1 (Wsb dead)
//   5. fuse_ln(M1,M2,s0,s1) -> d_out (xb/Wib dead)
//
// R11: thin the sync structure. R10 had 8 barriers/K-tile (2/phase, with
// back-to-back pairs separated only by an async gl_lds issue) and 2 vmcnt
// drains/K-tile; m201 (62% MfmaUtil, same tile/waves/MFMA-floor) has no
// redundant barrier pairs and ONE vmcnt per K-tile. Now: 4 barriers/K-tile
// (one per phase) + single vmcnt(4) at q3. Reads: q0:4 / q1:8 / q2:0 /
// q3:12 (all next-tile reads concentrated in q3, after its vmcnt+bar):
//   q0: stage Al(t+1) | bar | MFMA(0)[afE,bfr0] ∥ rd bfr1<-Bl(t)
//   q1: stage Bl(t+1) | bar | MFMA(1)[afE,bfr1] ∥ rd af<-Al(t)
//   q2:               | bar | MFMA(2)[afL,bfr0] (jj-major, no reads)
//   q3: stage Ae,Be(t+2) | vmcnt(4|0 tail) | bar
//       | MFMA(3)[afL,bfr1] ∥ rd af<-Ae(t+1), bfr0<-Be(t+1)
// vmcnt ledger at q3(t): outstanding = Ae,Be(t+1)[q3(t-1)] 4 + Al(t+1)[q0] 2
// + Bl(t+1)[q1] 2 + Ae,Be(t+2)[q3] 4 = 12; vmcnt(4) drains the 8 oldest =
// ALL of tile t+1 (then published by q3's bar, which precedes q3's reads).
// Skew audit (1-phase bound, q2 bar retained for this): every ds_read is
// drained by its consumer MFMA's in-order lgkm wait before the reading wave
// crosses the next barrier; every LDS region re-stage issues >=3 barriers
// after that. Per-element accumulation order unchanged (kh0->kh1; q2
// jj-major as R10) -> bitwise-identical C -> absmax unchanged.
// LDS swizzle: byte ^= (row&7)<<4 on pre-swizzled global source + ds_read
// address (conflict-free, R6-verified: 5e7 -> 0).

typedef unsigned short ushort_t;
typedef __attribute__((ext_vector_type(8))) __bf16 bf16x8;
typedef __attribute__((ext_vector_type(4))) float f32x4;

__device__ __forceinline__ ushort_t f2b(float f) {  // RNE
    unsigned u = __float_as_uint(f);
    unsigned r = (u + 0x7fffu + ((u >> 16) & 1u)) >> 16;
    return (ushort_t)r;
}
__device__ __forceinline__ float b2f(ushort_t u) {
    return __uint_as_float(((unsigned)u) << 16);
}

__device__ __forceinline__ void gl_lds16(const void* g, void* l) {
    __builtin_amdgcn_global_load_lds(
        (const __attribute__((address_space(1))) unsigned int*)(uintptr_t)g,
        (__attribute__((address_space(3))) unsigned int*)(uintptr_t)l,
        16, 0, 0);
}

// fast transcendentals: v_exp_f32 is 2^x, v_rcp_f32 ~1ulp — both far below
// the bf16 noise floor of this pipeline.
#define LOG2E 1.4426950408889634f
__device__ __forceinline__ float fexp2(float x) { return __builtin_amdgcn_exp2f(x); }
__device__ __forceinline__ float frcp(float x)  { return __builtin_amdgcn_rcpf(x); }
__device__ __forceinline__ float fsigmoid(float x) {
    return frcp(1.f + fexp2(-LOG2E * x));   // x=+inf -> 1, x=-inf -> 0
}
__device__ __forceinline__ float ftanh(float y) {
    return 1.f - 2.f * frcp(1.f + fexp2((2.f * LOG2E) * y));  // saturates +-1
}

// ---------------- casts ----------------
__global__ __launch_bounds__(256) void cast_bf16(const float* __restrict__ src,
                                                 ushort_t* __restrict__ dst, long n) {
    long i = ((long)blockIdx.x * 256 + threadIdx.x) * 4;
    if (i + 3 < n) {
        float4 v = *(const float4*)(src + i);
        ushort4 u;
        u.x = f2b(v.x); u.y = f2b(v.y); u.z = f2b(v.z); u.w = f2b(v.w);
        *(ushort4*)(dst + i) = u;
    }
}

// dst is B x 2048, src0/src1 are B x 1024 each
__global__ __launch_bounds__(256) void cast_concat(const float* __restrict__ s0,
                                                   const float* __restrict__ s1,
                                                   ushort_t* __restrict__ dst) {
    long i = ((long)blockIdx.x * 256 + threadIdx.x) * 4;  // index in dst
    long row = i >> 11;
    int  col = (int)(i & 2047);
    const float* src = (col < 1024) ? (s0 + row * 1024 + col)
                                    : (s1 + row * 1024 + (col - 1024));
    float4 v = *(const float4*)src;
    ushort4 u;
    u.x = f2b(v.x); u.y = f2b(v.y); u.z = f2b(v.z); u.w = f2b(v.w);
    *(ushort4*)(dst + i) = u;
}

// ------- GEMM (bf16 in): C[MxN] = A[MxK] @ W[NxK]^T, fp32 accum, bf16 out ---

// stage one 16KB unit (2 x global_load_lds per thread). kt = target K-tile.
__device__ __forceinline__ void stage2(const char* s0, const char* s1,
                                       int d0, int d1, char* ldsbase,
                                       int kt, int NT) {
    if (kt < NT) {
        long kb = (long)kt << 7;                 // 64 bf16 = 128 bytes
        char* lb = ldsbase + ((kt & 1) << 15);   // 32 KB buffer stride
        gl_lds16(s0 + kb, lb + d0);
        gl_lds16(s1 + kb, lb + d1);
    }
}

#define SGB_MFMA(n) __builtin_amdgcn_sched_group_barrier(0x8, n, 0)
#define SGB_DSR(n)  __builtin_amdgcn_sched_group_barrier(0x100, n, 0)

// 4 MFMAs of one ii-group (jj,kh inner; per-element kh0->kh1)
#define MFMA_II(Q, II, BS)                                                    \
    _Pragma("unroll") for (int jj = 0; jj < 2; jj++)                          \
        _Pragma("unroll") for (int kh = 0; kh < 2; kh++)                      \
            acc[Q][II][jj] = __builtin_amdgcn_mfma_f32_16x16x32_bf16(         \
                af[II][kh], bfr[BS][jj][kh], acc[Q][II][jj], 0, 0, 0);

// 8 MFMAs of one jj-group (ii,kh inner; per-element kh0->kh1)
#define MFMA_JJ(Q, JJ, BS)                                                    \
    _Pragma("unroll") for (int ii = 0; ii < 4; ii++)                          \
        _Pragma("unroll") for (int kh = 0; kh < 2; kh++)                      \
            acc[Q][ii][JJ] = __builtin_amdgcn_mfma_f32_16x16x32_bf16(         \
                af[ii][kh], bfr[BS][JJ][kh], acc[Q][ii][JJ], 0, 0, 0);

#define RD_B(BASE, R16, KC) (*(const bf16x8*)((BASE) + brow + (R16) * 2048 + (KC)))
#define RD_A(BASE, R16, KC) (*(const bf16x8*)((BASE) + arow + (R16) * 2048 + (KC)))

__global__ __launch_bounds__(512, 2) void gemm_bt(const ushort_t* __restrict__ A,
                                                  const ushort_t* __restrict__ W,
                                                  ushort_t* __restrict__ C,
                                                  int M, int N, int K) {
    (void)M;
    __shared__ __align__(16) ushort_t As[2][256 * 64];   // 64 KB
    __shared__ __align__(16) ushort_t Bs[2][256 * 64];   // 64 KB

    const int NT   = K >> 6;          // K-tiles of 64
    const int t    = threadIdx.x;
    const int lane = t & 63;
    const int w    = t >> 6;
    const int gm   = w >> 2;          // 0/1: wave's M-half of the 256 rows
    const int gn   = w & 3;           // 0..3: wave's N-quarter
    const int gb   = gn & 1;          // qn stagger bit
    const int wm   = gm << 7;
    const int wn   = gn << 6;

    // T1: bijective XCD swizzle (nwg % 8 == 0 here: 64*16 = 1024)
    const int nwg  = gridDim.x;
    const int cpx  = nwg >> 3;
    const int orig = blockIdx.x;
    const int wgid = (orig & 7) * cpx + (orig >> 3);
    const int NXB  = N >> 8;
    const int bx   = wgid % NXB;
    const int by   = wgid / NXB;
    const int bm0  = by << 8;
    const int bn0  = bx << 8;

    // ---- staging precompute: thread t, loads n=0,1 -> unit row u = n*64+(t>>3)
    const int u0r = t >> 3;
    const int chb = (t & 7) << 4;                        // dest chunk byte (linear)
    const int cbs = chb ^ ((u0r & 7) << 4);              // swizzled SOURCE col byte
    const int ur0 = u0r, ur1 = 64 + u0r;                 // (ur&7 identical for both)

    // region maps (unit row -> actual tile row); all preserve row mod 8 == ur mod 8
    #define AER(ur) ((ur) < 64 ? (ur) : (ur) + 128)
    #define ALR(ur) ((ur) + 64)
    #define BER(ur) (((((ur) >> 5) >> 1) << 7) + ((((ur) >> 5) & 1) * 96) + ((ur) & 31))
    #define BLR(ur) ((ur) + 32 + (((ur) >> 6) << 6))

    const char* sAe0 = (const char*)(A + (long)(bm0 + AER(ur0)) * K) + cbs;
    const char* sAe1 = (const char*)(A + (long)(bm0 + AER(ur1)) * K) + cbs;
    const char* sAl0 = (const char*)(A + (long)(bm0 + ALR(ur0)) * K) + cbs;
    const char* sAl1 = (const char*)(A + (long)(bm0 + ALR(ur1)) * K) + cbs;
    const char* sBe0 = (const char*)(W + (long)(bn0 + BER(ur0)) * K) + cbs;
    const char* sBe1 = (const char*)(W + (long)(bn0 + BER(ur1)) * K) + cbs;
    const char* sBl0 = (const char*)(W + (long)(bn0 + BLR(ur0)) * K) + cbs;
    const char* sBl1 = (const char*)(W + (long)(bn0 + BLR(ur1)) * K) + cbs;

    const int dAe0 = AER(ur0) * 128 + chb, dAe1 = AER(ur1) * 128 + chb;
    const int dAl0 = ALR(ur0) * 128 + chb, dAl1 = ALR(ur1) * 128 + chb;
    const int dBe0 = BER(ur0) * 128 + chb, dBe1 = BER(ur1) * 128 + chb;
    const int dBl0 = BLR(ur0) * 128 + chb, dBl1 = BLR(ur1) * 128 + chb;

    char* Abase = (char*)&As[0][0];
    char* Bbase = (char*)&Bs[0][0];

    // ---- ds_read fragment precompute. Fragment row = 16*m + ml, so
    // row mod 8 = lane mod 8 -> read swizzle rsw = (lane&7)<<4.
    const int ml   = lane & 15;
    const int g    = lane >> 4;
    const int rsw  = (lane & 7) << 4;
    const int kc0  = ((g << 4)) ^ rsw;                   // kh=0 col byte
    const int kc1  = (64 | (g << 4)) ^ rsw;              // kh=1 col byte
    const int arow = (wm + ml) << 7;                     // byte row base
    const int brow = (wn + ml) << 7;

    f32x4 acc[4][4][2];                                  // [phase][ii][jj]
#pragma unroll
    for (int q = 0; q < 4; q++)
#pragma unroll
        for (int ii = 0; ii < 4; ii++)
#pragma unroll
            for (int jj = 0; jj < 2; jj++)
                acc[q][ii][jj] = (f32x4){0.f, 0.f, 0.f, 0.f};

    bf16x8 af[4][2];          // A frags: holds Ae for q0/q1, Al for q2/q3
    bf16x8 bfr[2][2][2];      // B frags: [set][jj][kh]; set0=Be, set1=Bl

    // ---- prologue: tile0 complete, then tile1 early units (stay in flight)
    stage2(sAe0, sAe1, dAe0, dAe1, Abase, 0, NT);
    stage2(sAl0, sAl1, dAl0, dAl1, Abase, 0, NT);
    stage2(sBe0, sBe1, dBe0, dBe1, Bbase, 0, NT);
    stage2(sBl0, sBl1, dBl0, dBl1, Bbase, 0, NT);
    stage2(sAe0, sAe1, dAe0, dAe1, Abase, 1, NT);
    stage2(sBe0, sBe1, dBe0, dBe1, Bbase, 1, NT);
    asm volatile("s_waitcnt vmcnt(4)" ::: "memory");     // tile 0 landed
    __builtin_amdgcn_s_barrier();
    // preload tile-0 q0 operands (consumed at q0's MFMA via compiler lgkm)
#pragma unroll
    for (int jj = 0; jj < 2; jj++) {
        bfr[0][jj][0] = RD_B(Bbase, (gb << 1) + jj, kc0);
        bfr[0][jj][1] = RD_B(Bbase, (gb << 1) + jj, kc1);
    }
#pragma unroll
    for (int ii = 0; ii < 4; ii++) {
        af[ii][0] = RD_A(Abase, (gm << 2) + ii, kc0);
        af[ii][1] = RD_A(Abase, (gm << 2) + ii, kc1);
    }

    for (int kt = 0; kt < NT; ++kt) {
        const char* AbT = Abase + ((kt & 1) << 15);         // tile t buffer
        const char* BbT = Bbase + ((kt & 1) << 15);
        const char* AbN = Abase + (((kt + 1) & 1) << 15);   // tile t+1 buffer
        const char* BbN = Bbase + (((kt + 1) & 1) << 15);
        const int rB1 = (1 ^ gb) << 1;   // Bl rows for bfr1
        const int rB0 = gb << 1;         // Be rows for bfr0
        const int rA1 = (1 ^ gm) << 2;   // Al rows
        const int rA0 = gm << 2;         // Ae rows

        // ---- q0: MFMA(afE,bfr0) ∥ read bfr1<-Bl(t)
        stage2(sAl0, sAl1, dAl0, dAl1, Abase, kt + 1, NT);
        __builtin_amdgcn_s_barrier();
        __builtin_amdgcn_s_setprio(1);
        MFMA_II(0, 0, 0); SGB_MFMA(4);
        bfr[1][0][0] = RD_B(BbT, rB1 + 0, kc0); SGB_DSR(1);
        MFMA_II(0, 1, 0); SGB_MFMA(4);
        bfr[1][0][1] = RD_B(BbT, rB1 + 0, kc1); SGB_DSR(1);
        MFMA_II(0, 2, 0); SGB_MFMA(4);
        bfr[1][1][0] = RD_B(BbT, rB1 + 1, kc0); SGB_DSR(1);
        MFMA_II(0, 3, 0); SGB_MFMA(4);
        bfr[1][1][1] = RD_B(BbT, rB1 + 1, kc1); SGB_DSR(1);
        __builtin_amdgcn_s_setprio(0);

        // ---- q1: MFMA(afE,bfr1) ∥ read af<-Al(t)  (af[ii] dead after its group)
        stage2(sBl0, sBl1, dBl0, dBl1, Bbase, kt + 1, NT);
        __builtin_amdgcn_s_barrier();
        __builtin_amdgcn_s_setprio(1);
        MFMA_II(1, 0, 1); SGB_MFMA(4);
        af[0][0] = RD_A(AbT, rA1 + 0, kc0);
        af[0][1] = RD_A(AbT, rA1 + 0, kc1); SGB_DSR(2);
        MFMA_II(1, 1, 1); SGB_MFMA(4);
        af[1][0] = RD_A(AbT, rA1 + 1, kc0);
        af[1][1] = RD_A(AbT, rA1 + 1, kc1); SGB_DSR(2);
        MFMA_II(1, 2, 1); SGB_MFMA(4);
        af[2][0] = RD_A(AbT, rA1 + 2, kc0);
        af[2][1] = RD_A(AbT, rA1 + 2, kc1); SGB_DSR(2);
        MFMA_II(1, 3, 1); SGB_MFMA(4);
        af[3][0] = RD_A(AbT, rA1 + 3, kc0);
        af[3][1] = RD_A(AbT, rA1 + 3, kc1); SGB_DSR(2);
        __builtin_amdgcn_s_setprio(0);

        // ---- q2: MFMA(afL,bfr0) jj-major, no reads, no stage
        __builtin_amdgcn_s_barrier();
        __builtin_amdgcn_s_setprio(1);
        MFMA_JJ(2, 0, 0);
        MFMA_JJ(2, 1, 0);
        __builtin_amdgcn_s_setprio(0);

        // ---- q3: single vmcnt/K-tile | MFMA(afL,bfr1) ∥ read af<-Ae(t+1),
        //      bfr0<-Be(t+1)
        stage2(sAe0, sAe1, dAe0, dAe1, Abase, kt + 2, NT);
        stage2(sBe0, sBe1, dBe0, dBe1, Bbase, kt + 2, NT);
        if (kt < NT - 2) asm volatile("s_waitcnt vmcnt(4)" ::: "memory");
        else             asm volatile("s_waitcnt vmcnt(0)" ::: "memory");
        __builtin_amdgcn_s_barrier();
        __builtin_amdgcn_s_setprio(1);
        MFMA_II(3, 0, 1); SGB_MFMA(4);
        af[0][0] = RD_A(AbN, rA0 + 0, kc0);
        af[0][1] = RD_A(AbN, rA0 + 0, kc1);
        bfr[0][0][0] = RD_B(BbN, rB0 + 0, kc0);
        bfr[0][0][1] = RD_B(BbN, rB0 + 0, kc1); SGB_DSR(4);
        MFMA_II(3, 1, 1); SGB_MFMA(4);
        af[1][0] = RD_A(AbN, rA0 + 1, kc0);
        af[1][1] = RD_A(AbN, rA0 + 1, kc1);
        bfr[0][1][0] = RD_B(BbN, rB0 + 1, kc0);
        bfr[0][1][1] = RD_B(BbN, rB0 + 1, kc1); SGB_DSR(4);
        MFMA_II(3, 2, 1); SGB_MFMA(4);
        af[2][0] = RD_A(AbN, rA0 + 2, kc0);
        af[2][1] = RD_A(AbN, rA0 + 2, kc1); SGB_DSR(2);
        MFMA_II(3, 3, 1); SGB_MFMA(4);
        af[3][0] = RD_A(AbN, rA0 + 3, kc0);
        af[3][1] = RD_A(AbN, rA0 + 3, kc1); SGB_DSR(2);
        __builtin_amdgcn_s_setprio(0);
    }

    // C/D layout: col=lane&15, row=(lane>>4)*4+r  [m89/m91 verified]
    const int quad = (lane >> 4) << 2;
#pragma unroll
    for (int q = 0; q < 4; ++q) {
        const int qm = (q >> 1) ^ gm;
        const int qn = (q & 1) ^ gb;
#pragma unroll
        for (int ii = 0; ii < 4; ii++)
#pragma unroll
            for (int jj = 0; jj < 2; jj++)
#pragma unroll
                for (int r = 0; r < 4; r++) {
                    const int cm = bm0 + wm + ((qm << 2) + ii) * 16 + quad + r;
                    const int cn = bn0 + wn + ((qn << 1) + jj) * 16 + ml;
                    C[(long)cm * N + cn] = f2b(acc[q][ii][jj][r]);
                }
    }
}

// ---------------- fused LN(M1)+LN(M2) -> gates -> h -> LN(h) ----------------
__global__ __launch_bounds__(256) void fuse_ln(const ushort_t* __restrict__ M1,
                                               const ushort_t* __restrict__ M2,
                                               const float* __restrict__ p0,
                                               const float* __restrict__ p1,
                                               const float* __restrict__ lni_g,
                                               const float* __restrict__ lni_b,
                                               const float* __restrict__ lns_g,
                                               const float* __restrict__ lns_b,
                                               const float* __restrict__ lnh_g,
                                               const float* __restrict__ lnh_b,
                                               float* __restrict__ out) {
    const int row = blockIdx.x;
    const int t   = threadIdx.x;
    const long base = (long)row * 4096;

    __shared__ float sred[16];
    __shared__ float stats[8];

    float v1[4][4], v2[4][4];
    float s1 = 0.f, q1 = 0.f, s2 = 0.f, q2 = 0.f;
#pragma unroll
    for (int q = 0; q < 4; q++) {
        ushort4 a = *(const ushort4*)(M1 + base + q * 1024 + t * 4);
        ushort4 b = *(const ushort4*)(M2 + base + q * 1024 + t * 4);
        const ushort_t* ap = (const ushort_t*)&a;
        const ushort_t* bp = (const ushort_t*)&b;
#pragma unroll
        for (int j = 0; j < 4; j++) {
            float f1 = b2f(ap[j]); v1[q][j] = f1; s1 += f1; q1 += f1 * f1;
            float f2 = b2f(bp[j]); v2[q][j] = f2; s2 += f2; q2 += f2 * f2;
        }
    }
    float r4[4] = {s1, q1, s2, q2};
#pragma unroll
    for (int off = 32; off > 0; off >>= 1) {
#pragma unroll
        for (int i = 0; i < 4; i++) r4[i] += __shfl_down(r4[i], off, 64);
    }
    if ((t & 63) == 0) {
        int w = t >> 6;
#pragma unroll
        for (int i = 0; i < 4; i++) sred[w * 4 + i] = r4[i];
    }
    __syncthreads();
    if (t == 0) {
        float S1 = 0, Q1 = 0, S2 = 0, Q2 = 0;
        for (int w = 0; w < 4; w++) {
            S1 += sred[w * 4]; Q1 += sred[w * 4 + 1];
            S2 += sred[w * 4 + 2]; Q2 += sred[w * 4 + 3];
        }
        float mu1 = S1 * (1.f / 4096.f), mu2 = S2 * (1.f / 4096.f);
        float var1 = Q1 * (1.f / 4096.f) - mu1 * mu1;
        float var2 = Q2 * (1.f / 4096.f) - mu2 * mu2;
        stats[0] = mu1; stats[1] = rsqrtf(var1 + 1e-5f);
        stats[2] = mu2; stats[3] = rsqrtf(var2 + 1e-5f);
    }
    __syncthreads();
    const float mu1 = stats[0], rs1 = stats[1], mu2 = stats[2], rs2 = stats[3];

    float4 Gi[4], Bi[4], Gs[4], Bs[4];
#pragma unroll
    for (int q = 0; q < 4; q++) {
        Gi[q] = *(const float4*)(lni_g + q * 1024 + t * 4);
        Bi[q] = *(const float4*)(lni_b + q * 1024 + t * 4);
        Gs[q] = *(const float4*)(lns_g + q * 1024 + t * 4);
        Bs[q] = *(const float4*)(lns_b + q * 1024 + t * 4);
    }
    float4 P0 = *(const float4*)(p0 + (long)row * 1024 + t * 4);
    float4 P1 = *(const float4*)(p1 + (long)row * 1024 + t * 4);

    float h[4];
    float sh = 0.f, qh = 0.f;
#pragma unroll
    for (int j = 0; j < 4; j++) {
        float gq[4], snv = 0.f;
#pragma unroll
        for (int q = 0; q < 4; q++) {
            float a = (v1[q][j] - mu1) * rs1 * ((const float*)&Gi[q])[j] + ((const float*)&Bi[q])[j];
            float b = (v2[q][j] - mu2) * rs2 * ((const float*)&Gs[q])[j] + ((const float*)&Bs[q])[j];
            if (q == 2) snv = b;
            gq[q] = a + b;
        }
        float rg = fsigmoid(gq[0]);
        float ig = fsigmoid(gq[1]);
        float lg = fsigmoid(gq[3]);
        float ng = ftanh(gq[2] - rg * snv);
        float pp0 = ((const float*)&P0)[j], pp1 = ((const float*)&P1)[j];
        float hv = ng + ig * (lg * pp0 + (1.f - lg) * pp1 - ng);
        h[j] = hv; sh += hv; qh += hv * hv;
    }
    float r2[2] = {sh, qh};
#pragma unroll
    for (int off = 32; off > 0; off >>= 1) {
#pragma unroll
        for (int i = 0; i < 2; i++) r2[i] += __shfl_down(r2[i], off, 64);
    }
    if ((t & 63) == 0) {
        int w = t >> 6;
        sred[w * 4] = r2[0]; sred[w * 4 + 1] = r2[1];
    }
    __syncthreads();
    if (t == 0) {
        float S = 0, Q = 0;
        for (int w = 0; w < 4; w++) { S += sred[w * 4]; Q += sred[w * 4 + 1]; }
        float mu = S * (1.f / 1024.f);
        float var = Q * (1.f / 1024.f) - mu * mu;
        stats[4] = mu; stats[5] = rsqrtf(var + 1e-5f);
    }
    __syncthreads();
    const float muh = stats[4], rsh = stats[5];

    float4 Gh = *(const float4*)(lnh_g + t * 4);
    float4 Bh = *(const float4*)(lnh_b + t * 4);
    float4 O;
#pragma unroll
    for (int j = 0; j < 4; j++)
        ((float*)&O)[j] = (h[j] - muh) * rsh * ((const float*)&Gh)[j] + ((const float*)&Bh)[j];
    *(float4*)(out + (long)row * 1024 + t * 4) = O;
}

extern "C" void kernel_launch(void* const* d_in, const int* in_sizes, int n_in,
                              void* d_out, int out_size, void* d_ws, size_t ws_size,
                              hipStream_t stream) {
    const float* x     = (const float*)d_in[0];
    const float* s0    = (const float*)d_in[1];
    const float* s1    = (const float*)d_in[2];
    const float* Wi    = (const float*)d_in[3];
    const float* Ws    = (const float*)d_in[4];
    const float* lni_g = (const float*)d_in[5];
    const float* lni_b = (const float*)d_in[6];
    const float* lns_g = (const float*)d_in[7];
    const float* lns_b = (const float*)d_in[8];
    const float* lnh_g = (const float*)d_in[9];
    const float* lnh_b = (const float*)d_in[10];
    float* out = (float*)d_out;

    // ws: 256 MB = M1 [0,128MB) + M2 [128,256MB). d_out = 64 MB cast scratch.
    char* wsb = (char*)d_ws;
    ushort_t* M1  = (ushort_t*)wsb;                           // 128 MB
    ushort_t* M2  = (ushort_t*)(wsb + (((size_t)128) << 20)); // 128 MB
    ushort_t* Wsb = (ushort_t*)wsb;                           // 16 MB, aliases M1 (dead)
    ushort_t* sb  = (ushort_t*)d_out;                         // 64 MB, aliases out
    ushort_t* xb  = (ushort_t*)d_out;                         // 32 MB, aliases out
    ushort_t* Wib = (ushort_t*)((char*)d_out + (((size_t)32) << 20));  // 8 MB

    // 256x256 tiles: grid = (16384/256)*(4096/256) = 64*16 = 1024 blocks
    dim3 g(1024);

    // phase 1: casts for GEMM2
    cast_concat<<<32768, 256, 0, stream>>>(s0, s1, sb);
    cast_bf16<<<8192, 256, 0, stream>>>(Ws, Wsb, (long)4096 * 2048);
    // phase 2: GEMM2 (K=2048) -> M2
    gemm_bt<<<g, 512, 0, stream>>>(sb, Wsb, M2, 16384, 4096, 2048);
    // phase 3: casts for GEMM1 (overwrite sb, now dead)
    cast_bf16<<<16384, 256, 0, stream>>>(x, xb, (long)16384 * 1024);
    cast_bf16<<<4096, 256, 0, stream>>>(Wi, Wib, (long)4096 * 1024);
    // phase 4: GEMM1 (K=1024) -> M1 (overwrites Wsb, now dead)
    gemm_bt<<<g, 512, 0, stream>>>(xb, Wib, M1, 16384, 4096, 1024);
    // phase 5: fused epilogue -> d_out (overwrites xb/Wib, now dead)
    fuse_ln<<<16384, 256, 0, stream>>>(M1, M2, s0, s1, lni_g, lni_b, lns_g,
                                       lns_b, lnh_g, lnh_b, out);
}

// Round 8
// 698.540 us; speedup vs baseline: 1.0855x; 1.0639x over previous
//
#include <hip/hip_runtime.h>
#include <cstdint>

// LNGRU2dCell: B=16384, D=1024, S=1024
//   M1 = x @ Wi^T          (16384x4096, K=1024)
//   M2 = [s0|s1] @ Ws^T    (16384x4096, K=2048)
//   gates = LN(M1)*g1+b1 + LN(M2)*g2+b2 ; gate math ; out = LN(h)*gh+bh
//
// ws = 256 MB: M1 region [0,128MB) + M2 region [128,256MB).
// d_out (64 MB) doubles as cast scratch. Phases (lifetimes disjoint):
//   1. sb(64MB)->d_out, Wsb(16MB)->M1 region   [bf16 casts]
//   2. GEMM2 bf16 (sb,Wsb) -> M2
//   3. xb(32MB)+Wib(8MB)->d_out (sb dead)
//   4. GEMM1 bf16 (xb,Wib) -> M1 (Wsb dead)
//   5. fuse_ln(M1,M2,s0,s1) -> d_out (xb/Wib dead)
//
// R12: multi-row fuse_ln. Budget audit: GEMM2 256us + GEMM1 ~128us +
// casts ~60us leaves ~250us for fuse_ln (always dispatch #6, just under
// the 256us top-5 cutoff; ideal HBM time is only ~75us). Cause: block =
// 1 row; per thread 96B useful data vs 256B LN-params (16 float4, same
// for all 16384 blocks -> 1GB L2 re-read + 2.7x the data's issue slots).
// Now ROWS=8 rows/block (2048 blocks), params hoisted into registers
// outside the row loop. Per-row arithmetic/reduction order IDENTICAL ->
// bitwise-identical output. sred/stats LDS reuse across rows is safe:
// every rewrite is >=1 barrier after its last reader (4 bars/row as
// before). GEMM unchanged from R11 (49% MfmaUtil, 0 conflicts).

typedef unsigned short ushort_t;
typedef __attribute__((ext_vector_type(8))) __bf16 bf16x8;
typedef __attribute__((ext_vector_type(4))) float f32x4;

__device__ __forceinline__ ushort_t f2b(float f) {  // RNE
    unsigned u = __float_as_uint(f);
    unsigned r = (u + 0x7fffu + ((u >> 16) & 1u)) >> 16;
    return (ushort_t)r;
}
__device__ __forceinline__ float b2f(ushort_t u) {
    return __uint_as_float(((unsigned)u) << 16);
}

__device__ __forceinline__ void gl_lds16(const void* g, void* l) {
    __builtin_amdgcn_global_load_lds(
        (const __attribute__((address_space(1))) unsigned int*)(uintptr_t)g,
        (__attribute__((address_space(3))) unsigned int*)(uintptr_t)l,
        16, 0, 0);
}

// fast transcendentals: v_exp_f32 is 2^x, v_rcp_f32 ~1ulp — both far below
// the bf16 noise floor of this pipeline.
#define LOG2E 1.4426950408889634f
__device__ __forceinline__ float fexp2(float x) { return __builtin_amdgcn_exp2f(x); }
__device__ __forceinline__ float frcp(float x)  { return __builtin_amdgcn_rcpf(x); }
__device__ __forceinline__ float fsigmoid(float x) {
    return frcp(1.f + fexp2(-LOG2E * x));   // x=+inf -> 1, x=-inf -> 0
}
__device__ __forceinline__ float ftanh(float y) {
    return 1.f - 2.f * frcp(1.f + fexp2((2.f * LOG2E) * y));  // saturates +-1
}

// ---------------- casts ----------------
__global__ __launch_bounds__(256) void cast_bf16(const float* __restrict__ src,
                                                 ushort_t* __restrict__ dst, long n) {
    long i = ((long)blockIdx.x * 256 + threadIdx.x) * 4;
    if (i + 3 < n) {
        float4 v = *(const float4*)(src + i);
        ushort4 u;
        u.x = f2b(v.x); u.y = f2b(v.y); u.z = f2b(v.z); u.w = f2b(v.w);
        *(ushort4*)(dst + i) = u;
    }
}

// dst is B x 2048, src0/src1 are B x 1024 each
__global__ __launch_bounds__(256) void cast_concat(const float* __restrict__ s0,
                                                   const float* __restrict__ s1,
                                                   ushort_t* __restrict__ dst) {
    long i = ((long)blockIdx.x * 256 + threadIdx.x) * 4;  // index in dst
    long row = i >> 11;
    int  col = (int)(i & 2047);
    const float* src = (col < 1024) ? (s0 + row * 1024 + col)
                                    : (s1 + row * 1024 + (col - 1024));
    float4 v = *(const float4*)src;
    ushort4 u;
    u.x = f2b(v.x); u.y = f2b(v.y); u.z = f2b(v.z); u.w = f2b(v.w);
    *(ushort4*)(dst + i) = u;
}

// ------- GEMM (bf16 in): C[MxN] = A[MxK] @ W[NxK]^T, fp32 accum, bf16 out ---

// stage one 16KB unit (2 x global_load_lds per thread). kt = target K-tile.
__device__ __forceinline__ void stage2(const char* s0, const char* s1,
                                       int d0, int d1, char* ldsbase,
                                       int kt, int NT) {
    if (kt < NT) {
        long kb = (long)kt << 7;                 // 64 bf16 = 128 bytes
        char* lb = ldsbase + ((kt & 1) << 15);   // 32 KB buffer stride
        gl_lds16(s0 + kb, lb + d0);
        gl_lds16(s1 + kb, lb + d1);
    }
}

#define SGB_MFMA(n) __builtin_amdgcn_sched_group_barrier(0x8, n, 0)
#define SGB_DSR(n)  __builtin_amdgcn_sched_group_barrier(0x100, n, 0)

// 4 MFMAs of one ii-group (jj,kh inner; per-element kh0->kh1)
#define MFMA_II(Q, II, BS)                                                    \
    _Pragma("unroll") for (int jj = 0; jj < 2; jj++)                          \
        _Pragma("unroll") for (int kh = 0; kh < 2; kh++)                      \
            acc[Q][II][jj] = __builtin_amdgcn_mfma_f32_16x16x32_bf16(         \
                af[II][kh], bfr[BS][jj][kh], acc[Q][II][jj], 0, 0, 0);

// 8 MFMAs of one jj-group (ii,kh inner; per-element kh0->kh1)
#define MFMA_JJ(Q, JJ, BS)                                                    \
    _Pragma("unroll") for (int ii = 0; ii < 4; ii++)                          \
        _Pragma("unroll") for (int kh = 0; kh < 2; kh++)                      \
            acc[Q][ii][JJ] = __builtin_amdgcn_mfma_f32_16x16x32_bf16(         \
                af[ii][kh], bfr[BS][JJ][kh], acc[Q][ii][JJ], 0, 0, 0);

#define RD_B(BASE, R16, KC) (*(const bf16x8*)((BASE) + brow + (R16) * 2048 + (KC)))
#define RD_A(BASE, R16, KC) (*(const bf16x8*)((BASE) + arow + (R16) * 2048 + (KC)))

__global__ __launch_bounds__(512, 2) void gemm_bt(const ushort_t* __restrict__ A,
                                                  const ushort_t* __restrict__ W,
                                                  ushort_t* __restrict__ C,
                                                  int M, int N, int K) {
    (void)M;
    __shared__ __align__(16) ushort_t As[2][256 * 64];   // 64 KB
    __shared__ __align__(16) ushort_t Bs[2][256 * 64];   // 64 KB

    const int NT   = K >> 6;          // K-tiles of 64
    const int t    = threadIdx.x;
    const int lane = t & 63;
    const int w    = t >> 6;
    const int gm   = w >> 2;          // 0/1: wave's M-half of the 256 rows
    const int gn   = w & 3;           // 0..3: wave's N-quarter
    const int gb   = gn & 1;          // qn stagger bit
    const int wm   = gm << 7;
    const int wn   = gn << 6;

    // T1: bijective XCD swizzle (nwg % 8 == 0 here: 64*16 = 1024)
    const int nwg  = gridDim.x;
    const int cpx  = nwg >> 3;
    const int orig = blockIdx.x;
    const int wgid = (orig & 7) * cpx + (orig >> 3);
    const int NXB  = N >> 8;
    const int bx   = wgid % NXB;
    const int by   = wgid / NXB;
    const int bm0  = by << 8;
    const int bn0  = bx << 8;

    // ---- staging precompute: thread t, loads n=0,1 -> unit row u = n*64+(t>>3)
    const int u0r = t >> 3;
    const int chb = (t & 7) << 4;                        // dest chunk byte (linear)
    const int cbs = chb ^ ((u0r & 7) << 4);              // swizzled SOURCE col byte
    const int ur0 = u0r, ur1 = 64 + u0r;                 // (ur&7 identical for both)

    // region maps (unit row -> actual tile row); all preserve row mod 8 == ur mod 8
    #define AER(ur) ((ur) < 64 ? (ur) : (ur) + 128)
    #define ALR(ur) ((ur) + 64)
    #define BER(ur) (((((ur) >> 5) >> 1) << 7) + ((((ur) >> 5) & 1) * 96) + ((ur) & 31))
    #define BLR(ur) ((ur) + 32 + (((ur) >> 6) << 6))

    const char* sAe0 = (const char*)(A + (long)(bm0 + AER(ur0)) * K) + cbs;
    const char* sAe1 = (const char*)(A + (long)(bm0 + AER(ur1)) * K) + cbs;
    const char* sAl0 = (const char*)(A + (long)(bm0 + ALR(ur0)) * K) + cbs;
    const char* sAl1 = (const char*)(A + (long)(bm0 + ALR(ur1)) * K) + cbs;
    const char* sBe0 = (const char*)(W + (long)(bn0 + BER(ur0)) * K) + cbs;
    const char* sBe1 = (const char*)(W + (long)(bn0 + BER(ur1)) * K) + cbs;
    const char* sBl0 = (const char*)(W + (long)(bn0 + BLR(ur0)) * K) + cbs;
    const char* sBl1 = (const char*)(W + (long)(bn0 + BLR(ur1)) * K) + cbs;

    const int dAe0 = AER(ur0) * 128 + chb, dAe1 = AER(ur1) * 128 + chb;
    const int dAl0 = ALR(ur0) * 128 + chb, dAl1 = ALR(ur1) * 128 + chb;
    const int dBe0 = BER(ur0) * 128 + chb, dBe1 = BER(ur1) * 128 + chb;
    const int dBl0 = BLR(ur0) * 128 + chb, dBl1 = BLR(ur1) * 128 + chb;

    char* Abase = (char*)&As[0][0];
    char* Bbase = (char*)&Bs[0][0];

    // ---- ds_read fragment precompute. Fragment row = 16*m + ml, so
    // row mod 8 = lane mod 8 -> read swizzle rsw = (lane&7)<<4.
    const int ml   = lane & 15;
    const int g    = lane >> 4;
    const int rsw  = (lane & 7) << 4;
    const int kc0  = ((g << 4)) ^ rsw;                   // kh=0 col byte
    const int kc1  = (64 | (g << 4)) ^ rsw;              // kh=1 col byte
    const int arow = (wm + ml) << 7;                     // byte row base
    const int brow = (wn + ml) << 7;

    f32x4 acc[4][4][2];                                  // [phase][ii][jj]
#pragma unroll
    for (int q = 0; q < 4; q++)
#pragma unroll
        for (int ii = 0; ii < 4; ii++)
#pragma unroll
            for (int jj = 0; jj < 2; jj++)
                acc[q][ii][jj] = (f32x4){0.f, 0.f, 0.f, 0.f};

    bf16x8 af[4][2];          // A frags: holds Ae for q0/q1, Al for q2/q3
    bf16x8 bfr[2][2][2];      // B frags: [set][jj][kh]; set0=Be, set1=Bl

    // ---- prologue: tile0 complete, then tile1 early units (stay in flight)
    stage2(sAe0, sAe1, dAe0, dAe1, Abase, 0, NT);
    stage2(sAl0, sAl1, dAl0, dAl1, Abase, 0, NT);
    stage2(sBe0, sBe1, dBe0, dBe1, Bbase, 0, NT);
    stage2(sBl0, sBl1, dBl0, dBl1, Bbase, 0, NT);
    stage2(sAe0, sAe1, dAe0, dAe1, Abase, 1, NT);
    stage2(sBe0, sBe1, dBe0, dBe1, Bbase, 1, NT);
    asm volatile("s_waitcnt vmcnt(4)" ::: "memory");     // tile 0 landed
    __builtin_amdgcn_s_barrier();
    // preload tile-0 q0 operands (consumed at q0's MFMA via compiler lgkm)
#pragma unroll
    for (int jj = 0; jj < 2; jj++) {
        bfr[0][jj][0] = RD_B(Bbase, (gb << 1) + jj, kc0);
        bfr[0][jj][1] = RD_B(Bbase, (gb << 1) + jj, kc1);
    }
#pragma unroll
    for (int ii = 0; ii < 4; ii++) {
        af[ii][0] = RD_A(Abase, (gm << 2) + ii, kc0);
        af[ii][1] = RD_A(Abase, (gm << 2) + ii, kc1);
    }

    for (int kt = 0; kt < NT; ++kt) {
        const char* AbT = Abase + ((kt & 1) << 15);         // tile t buffer
        const char* BbT = Bbase + ((kt & 1) << 15);
        const char* AbN = Abase + (((kt + 1) & 1) << 15);   // tile t+1 buffer
        const char* BbN = Bbase + (((kt + 1) & 1) << 15);
        const int rB1 = (1 ^ gb) << 1;   // Bl rows for bfr1
        const int rB0 = gb << 1;         // Be rows for bfr0
        const int rA1 = (1 ^ gm) << 2;   // Al rows
        const int rA0 = gm << 2;         // Ae rows

        // ---- q0: MFMA(afE,bfr0) ∥ read bfr1<-Bl(t)
        stage2(sAl0, sAl1, dAl0, dAl1, Abase, kt + 1, NT);
        __builtin_amdgcn_s_barrier();
        __builtin_amdgcn_s_setprio(1);
        MFMA_II(0, 0, 0); SGB_MFMA(4);
        bfr[1][0][0] = RD_B(BbT, rB1 + 0, kc0); SGB_DSR(1);
        MFMA_II(0, 1, 0); SGB_MFMA(4);
        bfr[1][0][1] = RD_B(BbT, rB1 + 0, kc1); SGB_DSR(1);
        MFMA_II(0, 2, 0); SGB_MFMA(4);
        bfr[1][1][0] = RD_B(BbT, rB1 + 1, kc0); SGB_DSR(1);
        MFMA_II(0, 3, 0); SGB_MFMA(4);
        bfr[1][1][1] = RD_B(BbT, rB1 + 1, kc1); SGB_DSR(1);
        __builtin_amdgcn_s_setprio(0);

        // ---- q1: MFMA(afE,bfr1) ∥ read af<-Al(t)  (af[ii] dead after its group)
        stage2(sBl0, sBl1, dBl0, dBl1, Bbase, kt + 1, NT);
        __builtin_amdgcn_s_barrier();
        __builtin_amdgcn_s_setprio(1);
        MFMA_II(1, 0, 1); SGB_MFMA(4);
        af[0][0] = RD_A(AbT, rA1 + 0, kc0);
        af[0][1] = RD_A(AbT, rA1 + 0, kc1); SGB_DSR(2);
        MFMA_II(1, 1, 1); SGB_MFMA(4);
        af[1][0] = RD_A(AbT, rA1 + 1, kc0);
        af[1][1] = RD_A(AbT, rA1 + 1, kc1); SGB_DSR(2);
        MFMA_II(1, 2, 1); SGB_MFMA(4);
        af[2][0] = RD_A(AbT, rA1 + 2, kc0);
        af[2][1] = RD_A(AbT, rA1 + 2, kc1); SGB_DSR(2);
        MFMA_II(1, 3, 1); SGB_MFMA(4);
        af[3][0] = RD_A(AbT, rA1 + 3, kc0);
        af[3][1] = RD_A(AbT, rA1 + 3, kc1); SGB_DSR(2);
        __builtin_amdgcn_s_setprio(0);

        // ---- q2: MFMA(afL,bfr0) jj-major, no reads, no stage
        __builtin_amdgcn_s_barrier();
        __builtin_amdgcn_s_setprio(1);
        MFMA_JJ(2, 0, 0);
        MFMA_JJ(2, 1, 0);
        __builtin_amdgcn_s_setprio(0);

        // ---- q3: single vmcnt/K-tile | MFMA(afL,bfr1) ∥ read af<-Ae(t+1),
        //      bfr0<-Be(t+1)
        stage2(sAe0, sAe1, dAe0, dAe1, Abase, kt + 2, NT);
        stage2(sBe0, sBe1, dBe0, dBe1, Bbase, kt + 2, NT);
        if (kt < NT - 2) asm volatile("s_waitcnt vmcnt(4)" ::: "memory");
        else             asm volatile("s_waitcnt vmcnt(0)" ::: "memory");
        __builtin_amdgcn_s_barrier();
        __builtin_amdgcn_s_setprio(1);
        MFMA_II(3, 0, 1); SGB_MFMA(4);
        af[0][0] = RD_A(AbN, rA0 + 0, kc0);
        af[0][1] = RD_A(AbN, rA0 + 0, kc1);
        bfr[0][0][0] = RD_B(BbN, rB0 + 0, kc0);
        bfr[0][0][1] = RD_B(BbN, rB0 + 0, kc1); SGB_DSR(4);
        MFMA_II(3, 1, 1); SGB_MFMA(4);
        af[1][0] = RD_A(AbN, rA0 + 1, kc0);
        af[1][1] = RD_A(AbN, rA0 + 1, kc1);
        bfr[0][1][0] = RD_B(BbN, rB0 + 1, kc0);
        bfr[0][1][1] = RD_B(BbN, rB0 + 1, kc1); SGB_DSR(4);
        MFMA_II(3, 2, 1); SGB_MFMA(4);
        af[2][0] = RD_A(AbN, rA0 + 2, kc0);
        af[2][1] = RD_A(AbN, rA0 + 2, kc1); SGB_DSR(2);
        MFMA_II(3, 3, 1); SGB_MFMA(4);
        af[3][0] = RD_A(AbN, rA0 + 3, kc0);
        af[3][1] = RD_A(AbN, rA0 + 3, kc1); SGB_DSR(2);
        __builtin_amdgcn_s_setprio(0);
    }

    // C/D layout: col=lane&15, row=(lane>>4)*4+r  [m89/m91 verified]
    const int quad = (lane >> 4) << 2;
#pragma unroll
    for (int q = 0; q < 4; ++q) {
        const int qm = (q >> 1) ^ gm;
        const int qn = (q & 1) ^ gb;
#pragma unroll
        for (int ii = 0; ii < 4; ii++)
#pragma unroll
            for (int jj = 0; jj < 2; jj++)
#pragma unroll
                for (int r = 0; r < 4; r++) {
                    const int cm = bm0 + wm + ((qm << 2) + ii) * 16 + quad + r;
                    const int cn = bn0 + wn + ((qn << 1) + jj) * 16 + ml;
                    C[(long)cm * N + cn] = f2b(acc[q][ii][jj][r]);
                }
    }
}

// ---------------- fused LN(M1)+LN(M2) -> gates -> h -> LN(h) ----------------
// R12: ROWS rows per block; LN params hoisted to registers (were 256B/thread
// of L2 re-reads per row). Per-row arithmetic identical to R11.
#define FLROWS 8
__global__ __launch_bounds__(256) void fuse_ln(const ushort_t* __restrict__ M1,
                                               const ushort_t* __restrict__ M2,
                                               const float* __restrict__ p0,
                                               const float* __restrict__ p1,
                                               const float* __restrict__ lni_g,
                                               const float* __restrict__ lni_b,
                                               const float* __restrict__ lns_g,
                                               const float* __restrict__ lns_b,
                                               const float* __restrict__ lnh_g,
                                               const float* __restrict__ lnh_b,
                                               float* __restrict__ out) {
    const int t = threadIdx.x;
    const int row0 = blockIdx.x * FLROWS;

    __shared__ float sred[16];
    __shared__ float stats[8];

    // hoisted params (identical for every row)
    float4 Gi[4], Bi[4], Gs[4], Bs[4];
#pragma unroll
    for (int q = 0; q < 4; q++) {
        Gi[q] = *(const float4*)(lni_g + q * 1024 + t * 4);
        Bi[q] = *(const float4*)(lni_b + q * 1024 + t * 4);
        Gs[q] = *(const float4*)(lns_g + q * 1024 + t * 4);
        Bs[q] = *(const float4*)(lns_b + q * 1024 + t * 4);
    }
    const float4 Gh = *(const float4*)(lnh_g + t * 4);
    const float4 Bh = *(const float4*)(lnh_b + t * 4);

    for (int r = 0; r < FLROWS; ++r) {
        const int row = row0 + r;
        const long base = (long)row * 4096;

        float v1[4][4], v2[4][4];
        float s1 = 0.f, q1 = 0.f, s2 = 0.f, q2 = 0.f;
#pragma unroll
        for (int q = 0; q < 4; q++) {
            ushort4 a = *(const ushort4*)(M1 + base + q * 1024 + t * 4);
            ushort4 b = *(const ushort4*)(M2 + base + q * 1024 + t * 4);
            const ushort_t* ap = (const ushort_t*)&a;
            const ushort_t* bp = (const ushort_t*)&b;
#pragma unroll
            for (int j = 0; j < 4; j++) {
                float f1 = b2f(ap[j]); v1[q][j] = f1; s1 += f1; q1 += f1 * f1;
                float f2 = b2f(bp[j]); v2[q][j] = f2; s2 += f2; q2 += f2 * f2;
            }
        }
        float r4[4] = {s1, q1, s2, q2};
#pragma unroll
        for (int off = 32; off > 0; off >>= 1) {
#pragma unroll
            for (int i = 0; i < 4; i++) r4[i] += __shfl_down(r4[i], off, 64);
        }
        if ((t & 63) == 0) {
            int w = t >> 6;
#pragma unroll
            for (int i = 0; i < 4; i++) sred[w * 4 + i] = r4[i];
        }
        __syncthreads();
        if (t == 0) {
            float S1 = 0, Q1 = 0, S2 = 0, Q2 = 0;
            for (int w = 0; w < 4; w++) {
                S1 += sred[w * 4]; Q1 += sred[w * 4 + 1];
                S2 += sred[w * 4 + 2]; Q2 += sred[w * 4 + 3];
            }
            float mu1 = S1 * (1.f / 4096.f), mu2 = S2 * (1.f / 4096.f);
            float var1 = Q1 * (1.f / 4096.f) - mu1 * mu1;
            float var2 = Q2 * (1.f / 4096.f) - mu2 * mu2;
            stats[0] = mu1; stats[1] = rsqrtf(var1 + 1e-5f);
            stats[2] = mu2; stats[3] = rsqrtf(var2 + 1e-5f);
        }
        __syncthreads();
        const float mu1 = stats[0], rs1 = stats[1], mu2 = stats[2], rs2 = stats[3];

        float4 P0 = *(const float4*)(p0 + (long)row * 1024 + t * 4);
        float4 P1 = *(const float4*)(p1 + (long)row * 1024 + t * 4);

        float h[4];
        float sh = 0.f, qh = 0.f;
#pragma unroll
        for (int j = 0; j < 4; j++) {
            float gq[4], snv = 0.f;
#pragma unroll
            for (int q = 0; q < 4; q++) {
                float a = (v1[q][j] - mu1) * rs1 * ((const float*)&Gi[q])[j] + ((const float*)&Bi[q])[j];
                float b = (v2[q][j] - mu2) * rs2 * ((const float*)&Gs[q])[j] + ((const float*)&Bs[q])[j];
                if (q == 2) snv = b;
                gq[q] = a + b;
            }
            float rg = fsigmoid(gq[0]);
            float ig = fsigmoid(gq[1]);
            float lg = fsigmoid(gq[3]);
            float ng = ftanh(gq[2] - rg * snv);
            float pp0 = ((const float*)&P0)[j], pp1 = ((const float*)&P1)[j];
            float hv = ng + ig * (lg * pp0 + (1.f - lg) * pp1 - ng);
            h[j] = hv; sh += hv; qh += hv * hv;
        }
        float r2[2] = {sh, qh};
#pragma unroll
        for (int off = 32; off > 0; off >>= 1) {
#pragma unroll
            for (int i = 0; i < 2; i++) r2[i] += __shfl_down(r2[i], off, 64);
        }
        if ((t & 63) == 0) {
            int w = t >> 6;
            sred[w * 4] = r2[0]; sred[w * 4 + 1] = r2[1];
        }
        __syncthreads();
        if (t == 0) {
            float S = 0, Q = 0;
            for (int w = 0; w < 4; w++) { S += sred[w * 4]; Q += sred[w * 4 + 1]; }
            float mu = S * (1.f / 1024.f);
            float var = Q * (1.f / 1024.f) - mu * mu;
            stats[4] = mu; stats[5] = rsqrtf(var + 1e-5f);
        }
        __syncthreads();
        const float muh = stats[4], rsh = stats[5];

        float4 O;
#pragma unroll
        for (int j = 0; j < 4; j++)
            ((float*)&O)[j] = (h[j] - muh) * rsh * ((const float*)&Gh)[j] + ((const float*)&Bh)[j];
        *(float4*)(out + (long)row * 1024 + t * 4) = O;
    }
}

extern "C" void kernel_launch(void* const* d_in, const int* in_sizes, int n_in,
                              void* d_out, int out_size, void* d_ws, size_t ws_size,
                              hipStream_t stream) {
    const float* x     = (const float*)d_in[0];
    const float* s0    = (const float*)d_in[1];
    const float* s1    = (const float*)d_in[2];
    const float* Wi    = (const float*)d_in[3];
    const float* Ws    = (const float*)d_in[4];
    const float* lni_g = (const float*)d_in[5];
    const float* lni_b = (const float*)d_in[6];
    const float* lns_g = (const float*)d_in[7];
    const float* lns_b = (const float*)d_in[8];
    const float* lnh_g = (const float*)d_in[9];
    const float* lnh_b = (const float*)d_in[10];
    float* out = (float*)d_out;

    // ws: 256 MB = M1 [0,128MB) + M2 [128,256MB). d_out = 64 MB cast scratch.
    char* wsb = (char*)d_ws;
    ushort_t* M1  = (ushort_t*)wsb;                           // 128 MB
    ushort_t* M2  = (ushort_t*)(wsb + (((size_t)128) << 20)); // 128 MB
    ushort_t* Wsb = (ushort_t*)wsb;                           // 16 MB, aliases M1 (dead)
    ushort_t* sb  = (ushort_t*)d_out;                         // 64 MB, aliases out
    ushort_t* xb  = (ushort_t*)d_out;                         // 32 MB, aliases out
    ushort_t* Wib = (ushort_t*)((char*)d_out + (((size_t)32) << 20));  // 8 MB

    // 256x256 tiles: grid = (16384/256)*(4096/256) = 64*16 = 1024 blocks
    dim3 g(1024);

    // phase 1: casts for GEMM2
    cast_concat<<<32768, 256, 0, stream>>>(s0, s1, sb);
    cast_bf16<<<8192, 256, 0, stream>>>(Ws, Wsb, (long)4096 * 2048);
    // phase 2: GEMM2 (K=2048) -> M2
    gemm_bt<<<g, 512, 0, stream>>>(sb, Wsb, M2, 16384, 4096, 2048);
    // phase 3: casts for GEMM1 (overwrite sb, now dead)
    cast_bf16<<<16384, 256, 0, stream>>>(x, xb, (long)16384 * 1024);
    cast_bf16<<<4096, 256, 0, stream>>>(Wi, Wib, (long)4096 * 1024);
    // phase 4: GEMM1 (K=1024) -> M1 (overwrites Wsb, now dead)
    gemm_bt<<<g, 512, 0, stream>>>(xb, Wib, M1, 16384, 4096, 1024);
    // phase 5: fused epilogue -> d_out (overwrites xb/Wib, now dead)
    fuse_ln<<<16384 / FLROWS, 256, 0, stream>>>(M1, M2, s0, s1, lni_g, lni_b,
                                                lns_g, lns_b, lnh_g, lnh_b, out);
}